// Round 6
// baseline (2737.470 us; speedup 1.0000x reference)
//
#include <hip/hip_runtime.h>
#include <hip/hip_bf16.h>
#include <stdint.h>

// ---------------------------------------------------------------------------
// EncoderRNN: embedding-gather + bidirectional GRU (T=512,B=256,H=E=256) +
// tanh FC (512->512) + softmax FC (512->10).
//
// R10: R9's counters showed ~1500 VALU instr/step/wave vs ~350 written --
// the mixed "v"/"a" constraints made the allocator shuttle the 384-reg weight
// set between VGPR<->AGPR files around the epilogue EVERY step (the fixed
// 4.3us/step across R4-R9). Fix: unambiguous, pressure-safe file assignment:
//   AGPR = 8 weight pairs (256 regs, exactly full), pinned once via
//          asm(""::"+a"), only ever used as "a" MFMA operands.
//   VGPR = 4 weight pairs (128) used only as "v" + accs forced "+v" (48)
//          + working set (~75) -> peak ~250 < 256, no live-range splits.
// Rec geometry from R9 (128 blocks x 256 thr, 4 batch rows, gi in LDS dbuf).
// gemm role un-fused (would inherit the 500-reg budget): R8's standalone
// gi_gemm (~10us/chunk) serial on the stream.
// ---------------------------------------------------------------------------

using short8  = __attribute__((ext_vector_type(8))) short;
using float4v = __attribute__((ext_vector_type(4))) float;

// ws layout (bytes)
constexpr size_t OFF_FLAG = 0;
constexpr size_t OFF_HST  = 64;                      // fp32 [2][256][256]
constexpr size_t OFF_REP  = OFF_HST  + 524288;       // bf16 [256][512]
constexpr size_t OFF_HID  = OFF_REP  + 262144;       // bf16 [256][512]
constexpr size_t OFF_WIHF = OFF_HID  + 262144;       // bf16 [768][256]
constexpr size_t OFF_WHHF = OFF_WIHF + 393216;
constexpr size_t OFF_WIHB = OFF_WHHF + 393216;
constexpr size_t OFF_WHHB = OFF_WIHB + 393216;
constexpr size_t OFF_BIHF = OFF_WHHB + 393216;       // bf16 [768]
constexpr size_t OFF_BHHF = OFF_BIHF + 1536;
constexpr size_t OFF_BIHB = OFF_BHHF + 1536;
constexpr size_t OFF_BHHB = OFF_BIHB + 1536;
constexpr size_t OFF_W1   = OFF_BHHB + 1536;         // bf16 [512][512]
constexpr size_t OFF_B1   = OFF_W1   + 524288;       // bf16 [512]
constexpr size_t OFF_W2   = OFF_B1   + 1024;         // bf16 [10][512]
constexpr size_t OFF_B2   = OFF_W2   + 10240;        // bf16 [10]
constexpr size_t OFF_EMB  = OFF_B2   + 64;           // bf16 [50000][256]
constexpr size_t OFF_GI   = OFF_EMB  + 25600000;     // fp32 gi ping-pong

// rec gi LDS: 4 rows x 3088B per buffer, double-buffered
constexpr int GI_ROWB = 3088;                        // 772 dw (2-way banks)
constexpr int GI_BUF4 = 4 * GI_ROWB;                 // 12352

__device__ inline float asf(unsigned int u) {
  union { unsigned int i; float f; } v; v.i = u; return v.f;
}
__device__ inline float bf2f(unsigned short u) {
  return asf(((unsigned int)u) << 16);
}
__device__ inline unsigned short f2bf(float f) {
  union { float f; unsigned int i; } v; v.f = f;
  unsigned int i = v.i;
  return (unsigned short)((i + 0x7FFFu + ((i >> 16) & 1u)) >> 16);  // RNE
}
__device__ inline float fast_sigmoid(float x) {
  float e = __builtin_amdgcn_exp2f(-1.442695040888963f * x);
  return __builtin_amdgcn_rcpf(1.0f + e);
}
__device__ inline float fast_tanh(float x) {
  float e = __builtin_amdgcn_exp2f(2.885390081777927f * x);
  return 1.0f - 2.0f * __builtin_amdgcn_rcpf(e + 1.0f);
}

// MFMA with acc pinned to arch VGPRs (epilogue reads it move-free);
// B operand either VGPR- or AGPR-resident.
__device__ __forceinline__ void mfma_vv(float4v& acc, short8 a, short8 b) {
  asm("v_mfma_f32_16x16x32_bf16 %0, %1, %2, %0" : "+v"(acc) : "v"(a), "v"(b));
}
__device__ __forceinline__ void mfma_va(float4v& acc, short8 a, short8 b) {
  asm("v_mfma_f32_16x16x32_bf16 %0, %1, %2, %0" : "+v"(acc) : "v"(a), "a"(b));
}
// one-time pin of a weight fragment into the AGPR file
#define PIN_AGPR(x) asm("" : "+a"(x))

// async global->LDS DMA, 16B per lane, LDS dest = uniform base + lane*16
__device__ __forceinline__ void async_copy16(char* lds, const char* g) {
  __builtin_amdgcn_global_load_lds(
      (const __attribute__((address_space(1))) unsigned int*)g,
      (__attribute__((address_space(3))) unsigned int*)lds, 16, 0, 0);
}

// ---------------------------------------------------------------------------
__global__ void detect(const unsigned int* __restrict__ w, int* __restrict__ flag) {
  __shared__ int bad;
  if (threadIdx.x == 0) bad = 0;
  __syncthreads();
  int local = 0;
  for (int i = threadIdx.x; i < 4096; i += 256) {
    const unsigned int x = w[i];
    if (((x >> 7) & 0xFFu) > 0x7Bu) local = 1;
  }
  if (local) atomicOr(&bad, 1);
  __syncthreads();
  if (threadIdx.x == 0) flag[0] = bad ? 1 : 0;
}

struct Ptrs { const void* p[12]; };

__global__ __launch_bounds__(256) void cvt_seg(Ptrs ps, char* __restrict__ wsb,
                                               const int* __restrict__ flag) {
  const int cnt[12] = {196608, 196608, 196608, 196608, 768, 768, 768, 768,
                       262144, 512, 5120, 10};
  const int off[12] = {(int)OFF_WIHF, (int)OFF_WHHF, (int)OFF_WIHB, (int)OFF_WHHB,
                       (int)OFF_BIHF, (int)OFF_BHHF, (int)OFF_BIHB, (int)OFF_BHHB,
                       (int)OFF_W1,   (int)OFF_B1,   (int)OFF_W2,   (int)OFF_B2};
  const int seg = blockIdx.y;
  const int n = cnt[seg];
  unsigned short* dst = (unsigned short*)(wsb + off[seg]);
  const int stride = gridDim.x * blockDim.x;
  int i = blockIdx.x * blockDim.x + threadIdx.x;
  if (flag[0]) {
    const float* s = (const float*)ps.p[seg];
    for (; i < n; i += stride) dst[i] = f2bf(s[i]);
  } else {
    const unsigned short* s = (const unsigned short*)ps.p[seg];
    for (; i < n; i += stride) dst[i] = s[i];
  }
}

__global__ __launch_bounds__(256) void cvt_emb(const void* __restrict__ src,
                                               unsigned short* __restrict__ dst,
                                               const int* __restrict__ flag) {
  const int n = 12800000;
  const int stride = gridDim.x * blockDim.x;
  int i = blockIdx.x * blockDim.x + threadIdx.x;
  if (flag[0]) {
    const float* s = (const float*)src;
    for (; i < n; i += stride) dst[i] = f2bf(s[i]);
  } else {
    const unsigned short* s = (const unsigned short*)src;
    for (; i < n; i += stride) dst[i] = s[i];
  }
}

// ---------------------------------------------------------------------------
__global__ void zerok(uint4* __restrict__ p, int n4) {
  int i = blockIdx.x * blockDim.x + threadIdx.x;
  if (i < n4) { uint4 z; z.x = z.y = z.z = z.w = 0u; p[i] = z; }
}

// ---------------------------------------------------------------------------
// gi GEMM for one chunk. fp32 out. grid = (6, Tc*2, 2), block = 512.
__global__ __launch_bounds__(512, 4) void gi_gemm(
    const int* __restrict__ seqs, const int* __restrict__ lens,
    const unsigned short* __restrict__ emb,
    const unsigned short* __restrict__ WihF, const unsigned short* __restrict__ WihB,
    float* __restrict__ giF, float* __restrict__ giB,
    int t0f, int t0b)
{
  const int dir = blockIdx.z;
  const int nblk = blockIdx.x;
  const int tl = blockIdx.y >> 1;
  const int bh = blockIdx.y & 1;
  const int t = (dir ? t0b : t0f) + tl;

  int lo = 0, hi = 256;
  while (lo < hi) { int mid = (lo + hi) >> 1; if (lens[mid] > t) lo = mid + 1; else hi = mid; }
  const int n1 = lo;
  lo = 0; hi = 256;
  const int thr2 = 512 - t;
  while (lo < hi) { int mid = (lo + hi) >> 1; if (lens[mid] >= thr2) lo = mid + 1; else hi = mid; }
  const int n2 = lo;
  const int nneed = n1 < n2 ? n1 : n2;
  if (nneed <= bh * 128) return;

  const unsigned short* Wih = dir ? WihB : WihF;
  float* gi = dir ? giB : giF;

  __shared__ __attribute__((aligned(16))) short lA[128 * 256];

  const int tid = threadIdx.x;
  {
    const int kb = tid & 31;
    const int m0 = tid >> 5;
#pragma unroll
    for (int it = 0; it < 8; ++it) {
      const int m = it * 16 + m0;
      const int b = bh * 128 + m;
      const int tok = seqs[b * 512 + t];
      const uint4 v = *(const uint4*)(const void*)(emb + (size_t)tok * 256 + kb * 8);
      *(uint4*)(void*)(&lA[m * 256 + ((kb ^ (m & 7)) << 3)]) = v;
    }
  }
  __syncthreads();

  const int w = tid >> 6, lane = tid & 63, q = lane >> 4, n16 = lane & 15;
  const int mrow0 = (w & 3) * 32;
  const int ncol0 = (w >> 2) * 64;

  float4v acc[2][4];
#pragma unroll
  for (int mt = 0; mt < 2; ++mt)
#pragma unroll
    for (int nt = 0; nt < 4; ++nt) { float4v z = {0.f, 0.f, 0.f, 0.f}; acc[mt][nt] = z; }

#pragma unroll
  for (int ks = 0; ks < 8; ++ks) {
    short8 a[2];
#pragma unroll
    for (int mt = 0; mt < 2; ++mt) {
      const int m = mrow0 + mt * 16 + n16;
      const int kb = (ks * 4 + q) ^ (m & 7);
      a[mt] = *(const short8*)(const void*)(&lA[m * 256 + kb * 8]);
    }
#pragma unroll
    for (int nt = 0; nt < 4; ++nt) {
      const int j = nblk * 128 + ncol0 + nt * 16 + n16;
      const short8 bfr = *(const short8*)(const void*)(Wih + (size_t)j * 256 + ks * 32 + q * 8);
#pragma unroll
      for (int mt = 0; mt < 2; ++mt)
        acc[mt][nt] = __builtin_amdgcn_mfma_f32_16x16x32_bf16(a[mt], bfr, acc[mt][nt], 0, 0, 0);
    }
  }

#pragma unroll
  for (int mt = 0; mt < 2; ++mt)
#pragma unroll
    for (int nt = 0; nt < 4; ++nt)
#pragma unroll
      for (int r = 0; r < 4; ++r) {
        const int row = mrow0 + mt * 16 + q * 4 + r;
        const int b = bh * 128 + row;
        const int j = nblk * 128 + ncol0 + nt * 16 + n16;
        gi[((size_t)tl * 256 + b) * 768 + j] = acc[mt][nt][r];
      }
}

// ---------------------------------------------------------------------------
// GRU recurrence, weights register-resident with FIXED file assignment.
// grid = 128 (2 dir x 64 groups of 4 batch rows), block = 256 (1 wave/SIMD).
// Per wave: 12 (coltile,gate) weight pairs x 8 k-frags:
//   pairs 0..3  -> arch VGPRs (128 regs), used only as "v" operands
//   pairs 4..11 -> AGPRs (256 regs, file exactly full), pinned once,
//                  used only as "a" operands
//   accumulators -> arch VGPRs ("+v"), epilogue reads them move-free.
__global__ __launch_bounds__(256, 1) void rec_step(
    const int* __restrict__ lens,
    const unsigned short* __restrict__ WhhF, const unsigned short* __restrict__ WhhB,
    const unsigned short* __restrict__ bihF, const unsigned short* __restrict__ bhhF,
    const unsigned short* __restrict__ bihB, const unsigned short* __restrict__ bhhB,
    const float* __restrict__ gi_rd, float* __restrict__ hstate,
    unsigned short* __restrict__ rep,
    int t0f, int t0b, int Tc)
{
  __shared__ __attribute__((aligned(16))) char smem[16384 + 2 * GI_BUF4];
  const int bid = blockIdx.x;
  const int d = bid >> 6;
  const int g4 = bid & 63;
  const int tid = threadIdx.x, w = tid >> 6, lane = tid & 63, q = lane >> 4, n16 = lane & 15;

  const unsigned short* Whh = d ? WhhB : WhhF;
  const unsigned short* bih = d ? bihB : bihF;
  const unsigned short* bhh = d ? bhhB : bhhF;
  const float* gi = gi_rd + (size_t)d * (size_t)Tc * 196608;
  const int t0 = d ? t0b : t0f;

  short* hB0 = (short*)smem;            // 8KB [16][256] swizzled
  short* hB1 = (short*)(smem + 8192);   // 8KB
  char*  giL = smem + 16384;            // 2 x GI_BUF4

  // zero hB0+hB1 (rows 4..15 feed the MFMA A-tile and must stay zero)
  {
    uint4 z; z.x = z.y = z.z = z.w = 0u;
    uint4* p = (uint4*)smem;
    for (int i = tid; i < 1024; i += 256) p[i] = z;   // 16KB
  }

  // async prefetch of one gi tile (4 rows x 3072B); wave w loads row w.
  auto prefetch_gi = [&](int buf, int tl) {
    const char* srcB = (const char*)(gi + ((size_t)tl * 256 + g4 * 4) * 768);
    char* dstB = giL + buf * GI_BUF4;
#pragma unroll
    for (int i = 0; i < 3; ++i)
      async_copy16(dstB + w * GI_ROWB + i * 1024,
                   srcB + w * 3072 + i * 1024 + lane * 16);
  };

  // --- weight fragments: pair p = ct4*3+gate, wave w owns h-cols [4w..4w+4)*16
  const unsigned short* wbase = Whh + (size_t)q * 8;  // + j*256 + ks*32
  // pairs 0..3 -> VGPR file
  short8 wV[4][8];
#pragma unroll
  for (int p = 0; p < 4; ++p) {
    const int ct4 = p / 3, gate = p % 3;
    const int j = gate * 256 + (w * 4 + ct4) * 16 + n16;
#pragma unroll
    for (int ks = 0; ks < 8; ++ks)
      wV[p][ks] = *(const short8*)(const void*)(wbase + (size_t)j * 256 + ks * 32);
  }
  // pairs 4..11 -> AGPR file (pinned at init; only "a" uses below)
  short8 wA[8][8];
#pragma unroll
  for (int p8 = 0; p8 < 8; ++p8) {
    const int p = p8 + 4;
    const int ct4 = p / 3, gate = p % 3;
    const int j = gate * 256 + (w * 4 + ct4) * 16 + n16;
#pragma unroll
    for (int ks = 0; ks < 8; ++ks) {
      wA[p8][ks] = *(const short8*)(const void*)(wbase + (size_t)j * 256 + ks * 32);
      PIN_AGPR(wA[p8][ks]);
    }
  }

  float cr[4], cz[4], bin_[4], bhn_[4];
#pragma unroll
  for (int ct4 = 0; ct4 < 4; ++ct4) {
    const int j16 = (w * 4 + ct4) * 16 + n16;
    cr[ct4]   = bf2f(bih[j16])       + bf2f(bhh[j16]);
    cz[ct4]   = bf2f(bih[256 + j16]) + bf2f(bhh[256 + j16]);
    bin_[ct4] = bf2f(bih[512 + j16]);
    bhn_[ct4] = bf2f(bhh[512 + j16]);
  }

  int len_[4];
#pragma unroll
  for (int r = 0; r < 4; ++r) len_[r] = lens[g4 * 4 + r];

  float h[4][4];
#pragma unroll
  for (int ct4 = 0; ct4 < 4; ++ct4) {
    const int col = (w * 4 + ct4) * 16 + n16;
#pragma unroll
    for (int r = 0; r < 4; ++r)
      h[ct4][r] = (q == 0) ? hstate[d * 65536 + (g4 * 4 + r) * 256 + col] : 0.f;
  }

  __syncthreads();  // hB zero-init visible before row 0..3 writes

  if (q == 0) {
#pragma unroll
    for (int ct4 = 0; ct4 < 4; ++ct4) {
      const int col = (w * 4 + ct4) * 16 + n16;
      const int kb = col >> 3;
#pragma unroll
      for (int r = 0; r < 4; ++r)
        hB0[r * 256 + ((kb ^ (r & 7)) << 3) + (col & 7)] = (short)f2bf(h[ct4][r]);
    }
  }
  prefetch_gi(0, d ? (Tc - 1) : 0);
  __syncthreads();  // drains vmcnt: gi(s=0) resident in buf0; hB0 visible

  for (int s = 0; s < Tc; ++s) {
    const int t = t0 + (d ? (Tc - 1 - s) : s);

    if (s + 1 < Tc) prefetch_gi((s + 1) & 1, d ? (Tc - 2 - s) : (s + 1));

    const short* hRd = (s & 1) ? hB1 : hB0;
    short* hWr = (s & 1) ? hB0 : hB1;

    float4v acc[12];
#pragma unroll
    for (int p = 0; p < 12; ++p) { float4v z = {0.f, 0.f, 0.f, 0.f}; acc[p] = z; }

#pragma unroll
    for (int ks = 0; ks < 8; ++ks) {
      const int kb = (ks * 4 + q) ^ (n16 & 7);
      const short8 a = *(const short8*)(const void*)(&hRd[n16 * 256 + kb * 8]);
#pragma unroll
      for (int p = 0; p < 4; ++p) mfma_vv(acc[p], a, wV[p][ks]);
#pragma unroll
      for (int p8 = 0; p8 < 8; ++p8) mfma_va(acc[p8 + 4], a, wA[p8][ks]);
    }

    const char* gB = giL + (s & 1) * GI_BUF4;
    if (q == 0) {
#pragma unroll
      for (int ct4 = 0; ct4 < 4; ++ct4) {
        const int col = (w * 4 + ct4) * 16 + n16;
        const int kb = col >> 3;
#pragma unroll
        for (int r = 0; r < 4; ++r) {
          const float* grow = (const float*)(gB + r * GI_ROWB);
          const bool act = (t < len_[r]);
          const bool ug  = (t >= 512 - len_[r]);
          const float gr = ug ? grow[col] : 0.f;
          const float gz = ug ? grow[256 + col] : 0.f;
          const float gn = ug ? grow[512 + col] : 0.f;
          const float rr = fast_sigmoid(gr + cr[ct4] + acc[ct4 * 3 + 0][r]);
          const float zz = fast_sigmoid(gz + cz[ct4] + acc[ct4 * 3 + 1][r]);
          const float nn = fast_tanh(gn + bin_[ct4] + rr * (acc[ct4 * 3 + 2][r] + bhn_[ct4]));
          const float hnew = zz * (h[ct4][r] - nn) + nn;
          h[ct4][r] = act ? hnew : h[ct4][r];
          hWr[r * 256 + ((kb ^ (r & 7)) << 3) + (col & 7)] = (short)f2bf(h[ct4][r]);
        }
      }
    }
    __syncthreads();  // single barrier/step; drains gi prefetch + hB writes
  }

  if (q == 0) {
#pragma unroll
    for (int ct4 = 0; ct4 < 4; ++ct4) {
      const int col = (w * 4 + ct4) * 16 + n16;
#pragma unroll
      for (int r = 0; r < 4; ++r) {
        const int b = g4 * 4 + r;
        hstate[d * 65536 + b * 256 + col] = h[ct4][r];
        rep[b * 512 + d * 256 + col] = f2bf(h[ct4][r]);
      }
    }
  }
}

// ---------------------------------------------------------------------------
__global__ __launch_bounds__(256, 4) void head1(
    const unsigned short* __restrict__ rep, const unsigned short* __restrict__ W1,
    const unsigned short* __restrict__ b1, unsigned short* __restrict__ hid)
{
  const int mt = blockIdx.x;
  const int nh = blockIdx.y;
  const int tid = threadIdx.x, w = tid >> 6, lane = tid & 63, q = lane >> 4, n16 = lane & 15;

  float4v acc[4];
#pragma unroll
  for (int nt = 0; nt < 4; ++nt) { float4v z = {0.f, 0.f, 0.f, 0.f}; acc[nt] = z; }

#pragma unroll
  for (int ks = 0; ks < 16; ++ks) {
    const short8 a = *(const short8*)(const void*)(rep + (size_t)(mt * 16 + n16) * 512 + ks * 32 + q * 8);
#pragma unroll
    for (int nt = 0; nt < 4; ++nt) {
      const int n = nh * 256 + w * 64 + nt * 16 + n16;
      const short8 bfr = *(const short8*)(const void*)(W1 + (size_t)n * 512 + ks * 32 + q * 8);
      acc[nt] = __builtin_amdgcn_mfma_f32_16x16x32_bf16(a, bfr, acc[nt], 0, 0, 0);
    }
  }
#pragma unroll
  for (int nt = 0; nt < 4; ++nt)
#pragma unroll
    for (int r = 0; r < 4; ++r) {
      const int row = mt * 16 + q * 4 + r;
      const int col = nh * 256 + w * 64 + nt * 16 + n16;
      hid[row * 512 + col] = f2bf(fast_tanh(acc[nt][r] + bf2f(b1[col])));
    }
}

// ---------------------------------------------------------------------------
__global__ __launch_bounds__(64, 4) void head2(
    const unsigned short* __restrict__ hid, const unsigned short* __restrict__ W2,
    const unsigned short* __restrict__ b2, void* __restrict__ out,
    const int* __restrict__ flag)
{
  const int row = blockIdx.x;
  const int lane = threadIdx.x;
  const uint4 hv = *(const uint4*)(const void*)(hid + (size_t)row * 512 + lane * 8);
  const unsigned int hu[4] = {hv.x, hv.y, hv.z, hv.w};

  float logit[10];
#pragma unroll
  for (int j = 0; j < 10; ++j) {
    const uint4 wv = *(const uint4*)(const void*)(W2 + (size_t)j * 512 + lane * 8);
    const unsigned int wu[4] = {wv.x, wv.y, wv.z, wv.w};
    float s = 0.f;
#pragma unroll
    for (int i = 0; i < 4; ++i) {
      s = fmaf(asf(hu[i] << 16), asf(wu[i] << 16), s);
      s = fmaf(asf(hu[i] & 0xffff0000u), asf(wu[i] & 0xffff0000u), s);
    }
#pragma unroll
    for (int off = 32; off > 0; off >>= 1) s += __shfl_xor(s, off);
    logit[j] = s + bf2f(b2[j]);
  }
  float mx = logit[0];
#pragma unroll
  for (int j = 1; j < 10; ++j) mx = fmaxf(mx, logit[j]);
  float e[10]; float sum = 0.f;
#pragma unroll
  for (int j = 0; j < 10; ++j) { e[j] = __builtin_amdgcn_exp2f(1.442695040888963f * (logit[j] - mx)); sum += e[j]; }
  const float rs = __builtin_amdgcn_rcpf(sum);
  if (lane < 10) {
    float p = e[0];
#pragma unroll
    for (int j = 1; j < 10; ++j) p = (lane == j) ? e[j] : p;
    if (flag[0]) ((float*)out)[row * 10 + lane] = p * rs;
    else         ((unsigned short*)out)[row * 10 + lane] = f2bf(p * rs);
  }
}

// ---------------------------------------------------------------------------
extern "C" void kernel_launch(void* const* d_in, const int* in_sizes, int n_in,
                              void* d_out, int out_size, void* d_ws, size_t ws_size,
                              hipStream_t stream)
{
  (void)in_sizes; (void)n_in; (void)out_size;
  const int* seqs = (const int*)d_in[0];
  const int* lens = (const int*)d_in[1];
  char* ws = (char*)d_ws;

  int* flag = (int*)(ws + OFF_FLAG);
  float* hstate = (float*)(ws + OFF_HST);
  unsigned short* rep  = (unsigned short*)(ws + OFF_REP);
  unsigned short* hid  = (unsigned short*)(ws + OFF_HID);
  unsigned short* WihF = (unsigned short*)(ws + OFF_WIHF);
  unsigned short* WhhF = (unsigned short*)(ws + OFF_WHHF);
  unsigned short* WihB = (unsigned short*)(ws + OFF_WIHB);
  unsigned short* WhhB = (unsigned short*)(ws + OFF_WHHB);
  unsigned short* bihF = (unsigned short*)(ws + OFF_BIHF);
  unsigned short* bhhF = (unsigned short*)(ws + OFF_BHHF);
  unsigned short* bihB = (unsigned short*)(ws + OFF_BIHB);
  unsigned short* bhhB = (unsigned short*)(ws + OFF_BHHB);
  unsigned short* W1C  = (unsigned short*)(ws + OFF_W1);
  unsigned short* b1C  = (unsigned short*)(ws + OFF_B1);
  unsigned short* W2C  = (unsigned short*)(ws + OFF_W2);
  unsigned short* b2C  = (unsigned short*)(ws + OFF_B2);
  unsigned short* embC = (unsigned short*)(ws + OFF_EMB);

  detect<<<1, 256, 0, stream>>>((const unsigned int*)d_in[4], flag);
  Ptrs ps;
  ps.p[0] = d_in[3];  ps.p[1] = d_in[4];  ps.p[2] = d_in[7];  ps.p[3] = d_in[8];
  ps.p[4] = d_in[5];  ps.p[5] = d_in[6];  ps.p[6] = d_in[9];  ps.p[7] = d_in[10];
  ps.p[8] = d_in[11]; ps.p[9] = d_in[12]; ps.p[10] = d_in[13]; ps.p[11] = d_in[14];
  cvt_seg<<<dim3(64, 12), 256, 0, stream>>>(ps, ws, flag);
  cvt_emb<<<2048, 256, 0, stream>>>(d_in[2], embC, flag);

  zerok<<<128, 256, 0, stream>>>((uint4*)hstate, 32768);

  // Tc: ping-pong fp32 gi needs OFF_GI + 4*Tc*786432 bytes
  int Tc = 4;
  const int cands[4] = {32, 16, 8, 4};
  for (int i = 0; i < 4; ++i) {
    if (OFF_GI + 4ull * (size_t)cands[i] * 786432ull <= ws_size) { Tc = cands[i]; break; }
  }
  float* gi0 = (float*)(ws + OFF_GI);
  float* gi1 = gi0 + 2ull * (size_t)Tc * 196608ull;

  // prologue: chunk 0 into gi0
  gi_gemm<<<dim3(6, Tc * 2, 2), 512, 0, stream>>>(seqs, lens, embC, WihF, WihB,
      gi0, gi0 + (size_t)Tc * 196608ull, 0, 512 - Tc);

  const int NC = 512 / Tc;
  for (int c = 0; c < NC; ++c) {
    float* rd = (c & 1) ? gi1 : gi0;
    float* wr = (c & 1) ? gi0 : gi1;
    rec_step<<<128, 256, 0, stream>>>(lens, WhhF, WhhB,
        bihF, bhhF, bihB, bhhB, rd, hstate, rep,
        c * Tc, 512 - (c + 1) * Tc, Tc);
    if (c + 1 < NC) {
      gi_gemm<<<dim3(6, Tc * 2, 2), 512, 0, stream>>>(seqs, lens, embC, WihF, WihB,
          wr, wr + (size_t)Tc * 196608ull, (c + 1) * Tc, 512 - (c + 2) * Tc);
    }
  }
  head1<<<dim3(16, 2), 256, 0, stream>>>(rep, W1C, b1C, hid);
  head2<<<256, 64, 0, stream>>>(hid, W2C, b2C, d_out, flag);
}

// Round 7
// 2659.100 us; speedup vs baseline: 1.0295x; 1.0295x over previous
//
#include <hip/hip_runtime.h>
#include <hip/hip_bf16.h>
#include <stdint.h>

// ---------------------------------------------------------------------------
// EncoderRNN: embedding-gather + bidirectional GRU (T=512,B=256,H=E=256) +
// tanh FC (512->512) + softmax FC (512->10).
//
// R11: R10's step = 4.3us, of which ~2.9us is a stall that tracks ONLY the
// gi read path: gi is read while dirty in the writer XCD's L2 (~2-4k cyc
// remote latency) with just 3 loads in flight per wave (double-buffer +
// __syncthreads' vmcnt(0) drain each step) -> ~4B/cy = the 7.5-10GB/s/CU
// wall seen since R4. Fix the LATENCY, not bandwidth:
//   - 4 LDS gi buffers, prefetch issued 3 steps ahead (9 loads in flight)
//   - per-step: s_waitcnt vmcnt(9) + raw barrier before epilogue;
//     lgkmcnt(0) + raw barrier after (never drain vmcnt to 0 in-loop)
//   - gi_gemm writes gi with __builtin_nontemporal_store (no dirty L2)
// Register recipe unchanged from R10 (VGPR=256, wA in AGPRs, no spills --
// WRITE_SIZE proved outputs-only).
// ---------------------------------------------------------------------------

using short8  = __attribute__((ext_vector_type(8))) short;
using float4v = __attribute__((ext_vector_type(4))) float;

// ws layout (bytes)
constexpr size_t OFF_FLAG = 0;
constexpr size_t OFF_HST  = 64;                      // fp32 [2][256][256]
constexpr size_t OFF_REP  = OFF_HST  + 524288;       // bf16 [256][512]
constexpr size_t OFF_HID  = OFF_REP  + 262144;       // bf16 [256][512]
constexpr size_t OFF_WIHF = OFF_HID  + 262144;       // bf16 [768][256]
constexpr size_t OFF_WHHF = OFF_WIHF + 393216;
constexpr size_t OFF_WIHB = OFF_WHHF + 393216;
constexpr size_t OFF_WHHB = OFF_WIHB + 393216;
constexpr size_t OFF_BIHF = OFF_WHHB + 393216;       // bf16 [768]
constexpr size_t OFF_BHHF = OFF_BIHF + 1536;
constexpr size_t OFF_BIHB = OFF_BHHF + 1536;
constexpr size_t OFF_BHHB = OFF_BIHB + 1536;
constexpr size_t OFF_W1   = OFF_BHHB + 1536;         // bf16 [512][512]
constexpr size_t OFF_B1   = OFF_W1   + 524288;       // bf16 [512]
constexpr size_t OFF_W2   = OFF_B1   + 1024;         // bf16 [10][512]
constexpr size_t OFF_B2   = OFF_W2   + 10240;        // bf16 [10]
constexpr size_t OFF_EMB  = OFF_B2   + 64;           // bf16 [50000][256]
constexpr size_t OFF_GI   = OFF_EMB  + 25600000;     // fp32 gi ping-pong

// rec gi LDS: 4 rows x 3088B per buffer, 4 buffers (3-ahead pipeline)
constexpr int GI_ROWB = 3088;                        // 772 dw (2-way banks)
constexpr int GI_BUF4 = 4 * GI_ROWB;                 // 12352
constexpr int REC_LDS = 16384 + 4 * GI_BUF4;         // 65792 (>64K: dyn LDS)

__device__ inline float asf(unsigned int u) {
  union { unsigned int i; float f; } v; v.i = u; return v.f;
}
__device__ inline float bf2f(unsigned short u) {
  return asf(((unsigned int)u) << 16);
}
__device__ inline unsigned short f2bf(float f) {
  union { float f; unsigned int i; } v; v.f = f;
  unsigned int i = v.i;
  return (unsigned short)((i + 0x7FFFu + ((i >> 16) & 1u)) >> 16);  // RNE
}
__device__ inline float fast_sigmoid(float x) {
  float e = __builtin_amdgcn_exp2f(-1.442695040888963f * x);
  return __builtin_amdgcn_rcpf(1.0f + e);
}
__device__ inline float fast_tanh(float x) {
  float e = __builtin_amdgcn_exp2f(2.885390081777927f * x);
  return 1.0f - 2.0f * __builtin_amdgcn_rcpf(e + 1.0f);
}

// MFMA with acc pinned to arch VGPRs; B operand VGPR- or AGPR-resident.
__device__ __forceinline__ void mfma_vv(float4v& acc, short8 a, short8 b) {
  asm("v_mfma_f32_16x16x32_bf16 %0, %1, %2, %0" : "+v"(acc) : "v"(a), "v"(b));
}
__device__ __forceinline__ void mfma_va(float4v& acc, short8 a, short8 b) {
  asm("v_mfma_f32_16x16x32_bf16 %0, %1, %2, %0" : "+v"(acc) : "v"(a), "a"(b));
}
#define PIN_AGPR(x) asm("" : "+a"(x))

// async global->LDS DMA, 16B per lane, LDS dest = uniform base + lane*16
__device__ __forceinline__ void async_copy16(char* lds, const char* g) {
  __builtin_amdgcn_global_load_lds(
      (const __attribute__((address_space(1))) unsigned int*)g,
      (__attribute__((address_space(3))) unsigned int*)lds, 16, 0, 0);
}

// ---------------------------------------------------------------------------
__global__ void detect(const unsigned int* __restrict__ w, int* __restrict__ flag) {
  __shared__ int bad;
  if (threadIdx.x == 0) bad = 0;
  __syncthreads();
  int local = 0;
  for (int i = threadIdx.x; i < 4096; i += 256) {
    const unsigned int x = w[i];
    if (((x >> 7) & 0xFFu) > 0x7Bu) local = 1;
  }
  if (local) atomicOr(&bad, 1);
  __syncthreads();
  if (threadIdx.x == 0) flag[0] = bad ? 1 : 0;
}

struct Ptrs { const void* p[12]; };

__global__ __launch_bounds__(256) void cvt_seg(Ptrs ps, char* __restrict__ wsb,
                                               const int* __restrict__ flag) {
  const int cnt[12] = {196608, 196608, 196608, 196608, 768, 768, 768, 768,
                       262144, 512, 5120, 10};
  const int off[12] = {(int)OFF_WIHF, (int)OFF_WHHF, (int)OFF_WIHB, (int)OFF_WHHB,
                       (int)OFF_BIHF, (int)OFF_BHHF, (int)OFF_BIHB, (int)OFF_BHHB,
                       (int)OFF_W1,   (int)OFF_B1,   (int)OFF_W2,   (int)OFF_B2};
  const int seg = blockIdx.y;
  const int n = cnt[seg];
  unsigned short* dst = (unsigned short*)(wsb + off[seg]);
  const int stride = gridDim.x * blockDim.x;
  int i = blockIdx.x * blockDim.x + threadIdx.x;
  if (flag[0]) {
    const float* s = (const float*)ps.p[seg];
    for (; i < n; i += stride) dst[i] = f2bf(s[i]);
  } else {
    const unsigned short* s = (const unsigned short*)ps.p[seg];
    for (; i < n; i += stride) dst[i] = s[i];
  }
}

__global__ __launch_bounds__(256) void cvt_emb(const void* __restrict__ src,
                                               unsigned short* __restrict__ dst,
                                               const int* __restrict__ flag) {
  const int n = 12800000;
  const int stride = gridDim.x * blockDim.x;
  int i = blockIdx.x * blockDim.x + threadIdx.x;
  if (flag[0]) {
    const float* s = (const float*)src;
    for (; i < n; i += stride) dst[i] = f2bf(s[i]);
  } else {
    const unsigned short* s = (const unsigned short*)src;
    for (; i < n; i += stride) dst[i] = s[i];
  }
}

// ---------------------------------------------------------------------------
__global__ void zerok(uint4* __restrict__ p, int n4) {
  int i = blockIdx.x * blockDim.x + threadIdx.x;
  if (i < n4) { uint4 z; z.x = z.y = z.z = z.w = 0u; p[i] = z; }
}

// ---------------------------------------------------------------------------
// gi GEMM for one chunk. fp32 out via NON-TEMPORAL stores (gi is read-once by
// rec_step on other XCDs; nt avoids dirty-remote-L2 reads).
// grid = (6, Tc*2, 2), block = 512.
__global__ __launch_bounds__(512, 4) void gi_gemm(
    const int* __restrict__ seqs, const int* __restrict__ lens,
    const unsigned short* __restrict__ emb,
    const unsigned short* __restrict__ WihF, const unsigned short* __restrict__ WihB,
    float* __restrict__ giF, float* __restrict__ giB,
    int t0f, int t0b)
{
  const int dir = blockIdx.z;
  const int nblk = blockIdx.x;
  const int tl = blockIdx.y >> 1;
  const int bh = blockIdx.y & 1;
  const int t = (dir ? t0b : t0f) + tl;

  int lo = 0, hi = 256;
  while (lo < hi) { int mid = (lo + hi) >> 1; if (lens[mid] > t) lo = mid + 1; else hi = mid; }
  const int n1 = lo;
  lo = 0; hi = 256;
  const int thr2 = 512 - t;
  while (lo < hi) { int mid = (lo + hi) >> 1; if (lens[mid] >= thr2) lo = mid + 1; else hi = mid; }
  const int n2 = lo;
  const int nneed = n1 < n2 ? n1 : n2;
  if (nneed <= bh * 128) return;

  const unsigned short* Wih = dir ? WihB : WihF;
  float* gi = dir ? giB : giF;

  __shared__ __attribute__((aligned(16))) short lA[128 * 256];

  const int tid = threadIdx.x;
  {
    const int kb = tid & 31;
    const int m0 = tid >> 5;
#pragma unroll
    for (int it = 0; it < 8; ++it) {
      const int m = it * 16 + m0;
      const int b = bh * 128 + m;
      const int tok = seqs[b * 512 + t];
      const uint4 v = *(const uint4*)(const void*)(emb + (size_t)tok * 256 + kb * 8);
      *(uint4*)(void*)(&lA[m * 256 + ((kb ^ (m & 7)) << 3)]) = v;
    }
  }
  __syncthreads();

  const int w = tid >> 6, lane = tid & 63, q = lane >> 4, n16 = lane & 15;
  const int mrow0 = (w & 3) * 32;
  const int ncol0 = (w >> 2) * 64;

  float4v acc[2][4];
#pragma unroll
  for (int mt = 0; mt < 2; ++mt)
#pragma unroll
    for (int nt = 0; nt < 4; ++nt) { float4v z = {0.f, 0.f, 0.f, 0.f}; acc[mt][nt] = z; }

#pragma unroll
  for (int ks = 0; ks < 8; ++ks) {
    short8 a[2];
#pragma unroll
    for (int mt = 0; mt < 2; ++mt) {
      const int m = mrow0 + mt * 16 + n16;
      const int kb = (ks * 4 + q) ^ (m & 7);
      a[mt] = *(const short8*)(const void*)(&lA[m * 256 + kb * 8]);
    }
#pragma unroll
    for (int nt = 0; nt < 4; ++nt) {
      const int j = nblk * 128 + ncol0 + nt * 16 + n16;
      const short8 bfr = *(const short8*)(const void*)(Wih + (size_t)j * 256 + ks * 32 + q * 8);
#pragma unroll
      for (int mt = 0; mt < 2; ++mt)
        acc[mt][nt] = __builtin_amdgcn_mfma_f32_16x16x32_bf16(a[mt], bfr, acc[mt][nt], 0, 0, 0);
    }
  }

#pragma unroll
  for (int mt = 0; mt < 2; ++mt)
#pragma unroll
    for (int nt = 0; nt < 4; ++nt)
#pragma unroll
      for (int r = 0; r < 4; ++r) {
        const int row = mrow0 + mt * 16 + q * 4 + r;
        const int b = bh * 128 + row;
        const int j = nblk * 128 + ncol0 + nt * 16 + n16;
        __builtin_nontemporal_store(acc[mt][nt][r],
            &gi[((size_t)tl * 256 + b) * 768 + j]);
      }
}

// ---------------------------------------------------------------------------
// GRU recurrence, weights register-resident (R10 recipe), gi via 4-deep
// LDS prefetch pipeline with counted vmcnt (never drained to 0 in-loop).
// grid = 128 (2 dir x 64 groups of 4 batch rows), block = 256 (1 wave/SIMD).
__global__ __launch_bounds__(256, 1) void rec_step(
    const int* __restrict__ lens,
    const unsigned short* __restrict__ WhhF, const unsigned short* __restrict__ WhhB,
    const unsigned short* __restrict__ bihF, const unsigned short* __restrict__ bhhF,
    const unsigned short* __restrict__ bihB, const unsigned short* __restrict__ bhhB,
    const float* __restrict__ gi_rd, float* __restrict__ hstate,
    unsigned short* __restrict__ rep,
    int t0f, int t0b, int Tc)
{
  extern __shared__ char smem[];
  const int bid = blockIdx.x;
  const int d = bid >> 6;
  const int g4 = bid & 63;
  const int tid = threadIdx.x, w = tid >> 6, lane = tid & 63, q = lane >> 4, n16 = lane & 15;

  const unsigned short* Whh = d ? WhhB : WhhF;
  const unsigned short* bih = d ? bihB : bihF;
  const unsigned short* bhh = d ? bhhB : bhhF;
  const float* gi = gi_rd + (size_t)d * (size_t)Tc * 196608;
  const int t0 = d ? t0b : t0f;

  short* hB0 = (short*)smem;            // 8KB [16][256] swizzled
  short* hB1 = (short*)(smem + 8192);   // 8KB
  char*  giL = smem + 16384;            // 4 x GI_BUF4

  // zero hB0+hB1 (rows 4..15 feed the MFMA A-tile and must stay zero)
  {
    uint4 z; z.x = z.y = z.z = z.w = 0u;
    uint4* p = (uint4*)smem;
    for (int i = tid; i < 1024; i += 256) p[i] = z;   // 16KB
  }

  // async prefetch of one gi tile (4 rows x 3072B); wave w loads row w.
  auto prefetch_gi = [&](int buf, int tl) {
    const char* srcB = (const char*)(gi + ((size_t)tl * 256 + g4 * 4) * 768);
    char* dstB = giL + buf * GI_BUF4;
#pragma unroll
    for (int i = 0; i < 3; ++i)
      async_copy16(dstB + w * GI_ROWB + i * 1024,
                   srcB + w * 3072 + i * 1024 + lane * 16);
  };

  // --- weight fragments: pair p = ct4*3+gate, wave w owns h-cols [4w..4w+4)*16
  const unsigned short* wbase = Whh + (size_t)q * 8;  // + j*256 + ks*32
  // pairs 0..3 -> VGPR file
  short8 wV[4][8];
#pragma unroll
  for (int p = 0; p < 4; ++p) {
    const int ct4 = p / 3, gate = p % 3;
    const int j = gate * 256 + (w * 4 + ct4) * 16 + n16;
#pragma unroll
    for (int ks = 0; ks < 8; ++ks)
      wV[p][ks] = *(const short8*)(const void*)(wbase + (size_t)j * 256 + ks * 32);
  }
  // pairs 4..11 -> AGPR file (pinned at init; only "a" uses below)
  short8 wA[8][8];
#pragma unroll
  for (int p8 = 0; p8 < 8; ++p8) {
    const int p = p8 + 4;
    const int ct4 = p / 3, gate = p % 3;
    const int j = gate * 256 + (w * 4 + ct4) * 16 + n16;
#pragma unroll
    for (int ks = 0; ks < 8; ++ks) {
      wA[p8][ks] = *(const short8*)(const void*)(wbase + (size_t)j * 256 + ks * 32);
      PIN_AGPR(wA[p8][ks]);
    }
  }

  float cr[4], cz[4], bin_[4], bhn_[4];
#pragma unroll
  for (int ct4 = 0; ct4 < 4; ++ct4) {
    const int j16 = (w * 4 + ct4) * 16 + n16;
    cr[ct4]   = bf2f(bih[j16])       + bf2f(bhh[j16]);
    cz[ct4]   = bf2f(bih[256 + j16]) + bf2f(bhh[256 + j16]);
    bin_[ct4] = bf2f(bih[512 + j16]);
    bhn_[ct4] = bf2f(bhh[512 + j16]);
  }

  int len_[4];
#pragma unroll
  for (int r = 0; r < 4; ++r) len_[r] = lens[g4 * 4 + r];

  float h[4][4];
#pragma unroll
  for (int ct4 = 0; ct4 < 4; ++ct4) {
    const int col = (w * 4 + ct4) * 16 + n16;
#pragma unroll
    for (int r = 0; r < 4; ++r)
      h[ct4][r] = (q == 0) ? hstate[d * 65536 + (g4 * 4 + r) * 256 + col] : 0.f;
  }

  __syncthreads();  // hB zero-init visible before row 0..3 writes

  if (q == 0) {
#pragma unroll
    for (int ct4 = 0; ct4 < 4; ++ct4) {
      const int col = (w * 4 + ct4) * 16 + n16;
      const int kb = col >> 3;
#pragma unroll
      for (int r = 0; r < 4; ++r)
        hB0[r * 256 + ((kb ^ (r & 7)) << 3) + (col & 7)] = (short)f2bf(h[ct4][r]);
    }
  }
  // fill pipeline: tiles for steps 0,1,2 (Tc >= 4 always)
  for (int a = 0; a < 3; ++a)
    prefetch_gi(a, d ? (Tc - 1 - a) : a);
  __syncthreads();  // full drain once (prologue only); hB0 visible

  for (int s = 0; s < Tc; ++s) {
    const int t = t0 + (d ? (Tc - 1 - s) : s);

    // issue prefetch 3 steps ahead (clamped dummy at tail; its buffer is
    // never read again, so the overwrite is harmless)
    {
      const int sa = s + 3;
      const int tla = (sa < Tc) ? (d ? (Tc - 1 - sa) : sa) : (d ? 0 : (Tc - 1));
      prefetch_gi(sa & 3, tla);
    }

    const short* hRd = (s & 1) ? hB1 : hB0;
    short* hWr = (s & 1) ? hB0 : hB1;

    float4v acc[12];
#pragma unroll
    for (int p = 0; p < 12; ++p) { float4v z = {0.f, 0.f, 0.f, 0.f}; acc[p] = z; }

#pragma unroll
    for (int ks = 0; ks < 8; ++ks) {
      const int kb = (ks * 4 + q) ^ (n16 & 7);
      const short8 a = *(const short8*)(const void*)(&hRd[n16 * 256 + kb * 8]);
#pragma unroll
      for (int p = 0; p < 4; ++p) mfma_vv(acc[p], a, wV[p][ks]);
#pragma unroll
      for (int p8 = 0; p8 < 8; ++p8) mfma_va(acc[p8 + 4], a, wA[p8][ks]);
    }

    // step-s gi tile resident: allow only the 9 newest loads (s+1..s+3) to
    // remain in flight; barrier makes every wave's DMA visible block-wide.
    asm volatile("s_waitcnt vmcnt(9)" ::: "memory");
    __builtin_amdgcn_s_barrier();

    const char* gB = giL + (s & 3) * GI_BUF4;
    if (q == 0) {
#pragma unroll
      for (int ct4 = 0; ct4 < 4; ++ct4) {
        const int col = (w * 4 + ct4) * 16 + n16;
        const int kb = col >> 3;
#pragma unroll
        for (int r = 0; r < 4; ++r) {
          const float* grow = (const float*)(gB + r * GI_ROWB);
          const bool act = (t < len_[r]);
          const bool ug  = (t >= 512 - len_[r]);
          const float gr = ug ? grow[col] : 0.f;
          const float gz = ug ? grow[256 + col] : 0.f;
          const float gn = ug ? grow[512 + col] : 0.f;
          const float rr = fast_sigmoid(gr + cr[ct4] + acc[ct4 * 3 + 0][r]);
          const float zz = fast_sigmoid(gz + cz[ct4] + acc[ct4 * 3 + 1][r]);
          const float nn = fast_tanh(gn + bin_[ct4] + rr * (acc[ct4 * 3 + 2][r] + bhn_[ct4]));
          const float hnew = zz * (h[ct4][r] - nn) + nn;
          h[ct4][r] = act ? hnew : h[ct4][r];
          hWr[r * 256 + ((kb ^ (r & 7)) << 3) + (col & 7)] = (short)f2bf(h[ct4][r]);
        }
      }
    }
    // hWr visible + all LDS reads of this step's gi buffer retired before any
    // wave's next-iteration DMA can target it (buffer reuse at s+4).
    asm volatile("s_waitcnt lgkmcnt(0)" ::: "memory");
    __builtin_amdgcn_s_barrier();
  }

  if (q == 0) {
#pragma unroll
    for (int ct4 = 0; ct4 < 4; ++ct4) {
      const int col = (w * 4 + ct4) * 16 + n16;
#pragma unroll
      for (int r = 0; r < 4; ++r) {
        const int b = g4 * 4 + r;
        hstate[d * 65536 + b * 256 + col] = h[ct4][r];
        rep[b * 512 + d * 256 + col] = f2bf(h[ct4][r]);
      }
    }
  }
}

// ---------------------------------------------------------------------------
__global__ __launch_bounds__(256, 4) void head1(
    const unsigned short* __restrict__ rep, const unsigned short* __restrict__ W1,
    const unsigned short* __restrict__ b1, unsigned short* __restrict__ hid)
{
  const int mt = blockIdx.x;
  const int nh = blockIdx.y;
  const int tid = threadIdx.x, w = tid >> 6, lane = tid & 63, q = lane >> 4, n16 = lane & 15;

  float4v acc[4];
#pragma unroll
  for (int nt = 0; nt < 4; ++nt) { float4v z = {0.f, 0.f, 0.f, 0.f}; acc[nt] = z; }

#pragma unroll
  for (int ks = 0; ks < 16; ++ks) {
    const short8 a = *(const short8*)(const void*)(rep + (size_t)(mt * 16 + n16) * 512 + ks * 32 + q * 8);
#pragma unroll
    for (int nt = 0; nt < 4; ++nt) {
      const int n = nh * 256 + w * 64 + nt * 16 + n16;
      const short8 bfr = *(const short8*)(const void*)(W1 + (size_t)n * 512 + ks * 32 + q * 8);
      acc[nt] = __builtin_amdgcn_mfma_f32_16x16x32_bf16(a, bfr, acc[nt], 0, 0, 0);
    }
  }
#pragma unroll
  for (int nt = 0; nt < 4; ++nt)
#pragma unroll
    for (int r = 0; r < 4; ++r) {
      const int row = mt * 16 + q * 4 + r;
      const int col = nh * 256 + w * 64 + nt * 16 + n16;
      hid[row * 512 + col] = f2bf(fast_tanh(acc[nt][r] + bf2f(b1[col])));
    }
}

// ---------------------------------------------------------------------------
__global__ __launch_bounds__(64, 4) void head2(
    const unsigned short* __restrict__ hid, const unsigned short* __restrict__ W2,
    const unsigned short* __restrict__ b2, void* __restrict__ out,
    const int* __restrict__ flag)
{
  const int row = blockIdx.x;
  const int lane = threadIdx.x;
  const uint4 hv = *(const uint4*)(const void*)(hid + (size_t)row * 512 + lane * 8);
  const unsigned int hu[4] = {hv.x, hv.y, hv.z, hv.w};

  float logit[10];
#pragma unroll
  for (int j = 0; j < 10; ++j) {
    const uint4 wv = *(const uint4*)(const void*)(W2 + (size_t)j * 512 + lane * 8);
    const unsigned int wu[4] = {wv.x, wv.y, wv.z, wv.w};
    float s = 0.f;
#pragma unroll
    for (int i = 0; i < 4; ++i) {
      s = fmaf(asf(hu[i] << 16), asf(wu[i] << 16), s);
      s = fmaf(asf(hu[i] & 0xffff0000u), asf(wu[i] & 0xffff0000u), s);
    }
#pragma unroll
    for (int off = 32; off > 0; off >>= 1) s += __shfl_xor(s, off);
    logit[j] = s + bf2f(b2[j]);
  }
  float mx = logit[0];
#pragma unroll
  for (int j = 1; j < 10; ++j) mx = fmaxf(mx, logit[j]);
  float e[10]; float sum = 0.f;
#pragma unroll
  for (int j = 0; j < 10; ++j) { e[j] = __builtin_amdgcn_exp2f(1.442695040888963f * (logit[j] - mx)); sum += e[j]; }
  const float rs = __builtin_amdgcn_rcpf(sum);
  if (lane < 10) {
    float p = e[0];
#pragma unroll
    for (int j = 1; j < 10; ++j) p = (lane == j) ? e[j] : p;
    if (flag[0]) ((float*)out)[row * 10 + lane] = p * rs;
    else         ((unsigned short*)out)[row * 10 + lane] = f2bf(p * rs);
  }
}

// ---------------------------------------------------------------------------
extern "C" void kernel_launch(void* const* d_in, const int* in_sizes, int n_in,
                              void* d_out, int out_size, void* d_ws, size_t ws_size,
                              hipStream_t stream)
{
  (void)in_sizes; (void)n_in; (void)out_size;
  const int* seqs = (const int*)d_in[0];
  const int* lens = (const int*)d_in[1];
  char* ws = (char*)d_ws;

  // one-time: allow >64KB dynamic LDS for rec_step (host-side, capture-safe)
  static bool s_attr_done = false;
  if (!s_attr_done) {
    (void)hipFuncSetAttribute(reinterpret_cast<const void*>(rec_step),
                              hipFuncAttributeMaxDynamicSharedMemorySize, REC_LDS);
    s_attr_done = true;
  }

  int* flag = (int*)(ws + OFF_FLAG);
  float* hstate = (float*)(ws + OFF_HST);
  unsigned short* rep  = (unsigned short*)(ws + OFF_REP);
  unsigned short* hid  = (unsigned short*)(ws + OFF_HID);
  unsigned short* WihF = (unsigned short*)(ws + OFF_WIHF);
  unsigned short* WhhF = (unsigned short*)(ws + OFF_WHHF);
  unsigned short* WihB = (unsigned short*)(ws + OFF_WIHB);
  unsigned short* WhhB = (unsigned short*)(ws + OFF_WHHB);
  unsigned short* bihF = (unsigned short*)(ws + OFF_BIHF);
  unsigned short* bhhF = (unsigned short*)(ws + OFF_BHHF);
  unsigned short* bihB = (unsigned short*)(ws + OFF_BIHB);
  unsigned short* bhhB = (unsigned short*)(ws + OFF_BHHB);
  unsigned short* W1C  = (unsigned short*)(ws + OFF_W1);
  unsigned short* b1C  = (unsigned short*)(ws + OFF_B1);
  unsigned short* W2C  = (unsigned short*)(ws + OFF_W2);
  unsigned short* b2C  = (unsigned short*)(ws + OFF_B2);
  unsigned short* embC = (unsigned short*)(ws + OFF_EMB);

  detect<<<1, 256, 0, stream>>>((const unsigned int*)d_in[4], flag);
  Ptrs ps;
  ps.p[0] = d_in[3];  ps.p[1] = d_in[4];  ps.p[2] = d_in[7];  ps.p[3] = d_in[8];
  ps.p[4] = d_in[5];  ps.p[5] = d_in[6];  ps.p[6] = d_in[9];  ps.p[7] = d_in[10];
  ps.p[8] = d_in[11]; ps.p[9] = d_in[12]; ps.p[10] = d_in[13]; ps.p[11] = d_in[14];
  cvt_seg<<<dim3(64, 12), 256, 0, stream>>>(ps, ws, flag);
  cvt_emb<<<2048, 256, 0, stream>>>(d_in[2], embC, flag);

  zerok<<<128, 256, 0, stream>>>((uint4*)hstate, 32768);

  // Tc: ping-pong fp32 gi needs OFF_GI + 4*Tc*786432 bytes
  int Tc = 4;
  const int cands[4] = {32, 16, 8, 4};
  for (int i = 0; i < 4; ++i) {
    if (OFF_GI + 4ull * (size_t)cands[i] * 786432ull <= ws_size) { Tc = cands[i]; break; }
  }
  float* gi0 = (float*)(ws + OFF_GI);
  float* gi1 = gi0 + 2ull * (size_t)Tc * 196608ull;

  // prologue: chunk 0 into gi0
  gi_gemm<<<dim3(6, Tc * 2, 2), 512, 0, stream>>>(seqs, lens, embC, WihF, WihB,
      gi0, gi0 + (size_t)Tc * 196608ull, 0, 512 - Tc);

  const int NC = 512 / Tc;
  for (int c = 0; c < NC; ++c) {
    float* rd = (c & 1) ? gi1 : gi0;
    float* wr = (c & 1) ? gi0 : gi1;
    rec_step<<<128, 256, REC_LDS, stream>>>(lens, WhhF, WhhB,
        bihF, bhhF, bihB, bhhB, rd, hstate, rep,
        c * Tc, 512 - (c + 1) * Tc, Tc);
    if (c + 1 < NC) {
      gi_gemm<<<dim3(6, Tc * 2, 2), 512, 0, stream>>>(seqs, lens, embC, WihF, WihB,
          wr, wr + (size_t)Tc * 196608ull, (c + 1) * Tc, 512 - (c + 2) * Tc);
    }
  }
  head1<<<dim3(16, 2), 256, 0, stream>>>(rep, W1C, b1C, hid);
  head2<<<256, 64, 0, stream>>>(hid, W2C, b2C, d_out, flag);
}

// Round 8
// 1515.274 us; speedup vs baseline: 1.8066x; 1.7549x over previous
//
#include <hip/hip_runtime.h>
#include <hip/hip_bf16.h>
#include <stdint.h>

// ---------------------------------------------------------------------------
// EncoderRNN: embedding-gather + bidirectional GRU (T=512,B=256,H=E=256) +
// tanh FC (512->512) + softmax FC (512->10).
//
// R12: R11 killed the gi-latency theory (9-deep pipeline bought ~0). The
// remaining 2.5-3us/step stall is the SERIAL EPILOGUE: MFMA C-layout put all
// 4 batch rows in lane quadrant q=0 (rows 0-3), so 16/64 lanes did 16 outputs
// each (~48 LDS reads + ~400 VALU) fully exposed at 1 wave/SIMD. Fix: place
// batch row r at hB/A row 4r -> C row 4q = lane group q, reg 0 -> EVERY lane
// owns (batch row q, col n16): epilogue = 4 outputs/lane on all 64 lanes.
// Plus: gi tile read into regs at step top (hidden under MFMA); ONE barrier
// per step (s_waitcnt vmcnt(6) lgkmcnt(0) + s_barrier covers hWr visibility
// AND next step's gi; prefetch 3 ahead; vmcnt never drained in-loop).
// Weight recipe unchanged (wV 4 pairs VGPR / wA 8 pairs AGPR, VGPR=256).
// ---------------------------------------------------------------------------

using short8  = __attribute__((ext_vector_type(8))) short;
using float4v = __attribute__((ext_vector_type(4))) float;

// ws layout (bytes)
constexpr size_t OFF_FLAG = 0;
constexpr size_t OFF_HST  = 64;                      // fp32 [2][256][256]
constexpr size_t OFF_REP  = OFF_HST  + 524288;       // bf16 [256][512]
constexpr size_t OFF_HID  = OFF_REP  + 262144;       // bf16 [256][512]
constexpr size_t OFF_WIHF = OFF_HID  + 262144;       // bf16 [768][256]
constexpr size_t OFF_WHHF = OFF_WIHF + 393216;
constexpr size_t OFF_WIHB = OFF_WHHF + 393216;
constexpr size_t OFF_WHHB = OFF_WIHB + 393216;
constexpr size_t OFF_BIHF = OFF_WHHB + 393216;       // bf16 [768]
constexpr size_t OFF_BHHF = OFF_BIHF + 1536;
constexpr size_t OFF_BIHB = OFF_BHHF + 1536;
constexpr size_t OFF_BHHB = OFF_BIHB + 1536;
constexpr size_t OFF_W1   = OFF_BHHB + 1536;         // bf16 [512][512]
constexpr size_t OFF_B1   = OFF_W1   + 524288;       // bf16 [512]
constexpr size_t OFF_W2   = OFF_B1   + 1024;         // bf16 [10][512]
constexpr size_t OFF_B2   = OFF_W2   + 10240;        // bf16 [10]
constexpr size_t OFF_EMB  = OFF_B2   + 64;           // bf16 [50000][256]
constexpr size_t OFF_GI   = OFF_EMB  + 25600000;     // fp32 gi ping-pong

// rec gi LDS: 4 rows x 3088B per buffer, 4 buffers (3-ahead pipeline)
constexpr int GI_ROWB = 3088;                        // 772 dw (2-way banks)
constexpr int GI_BUF4 = 4 * GI_ROWB;                 // 12352
constexpr int REC_LDS = 16384 + 4 * GI_BUF4;         // 65792 (>64K: dyn LDS)

__device__ inline float asf(unsigned int u) {
  union { unsigned int i; float f; } v; v.i = u; return v.f;
}
__device__ inline float bf2f(unsigned short u) {
  return asf(((unsigned int)u) << 16);
}
__device__ inline unsigned short f2bf(float f) {
  union { float f; unsigned int i; } v; v.f = f;
  unsigned int i = v.i;
  return (unsigned short)((i + 0x7FFFu + ((i >> 16) & 1u)) >> 16);  // RNE
}
__device__ inline float fast_sigmoid(float x) {
  float e = __builtin_amdgcn_exp2f(-1.442695040888963f * x);
  return __builtin_amdgcn_rcpf(1.0f + e);
}
__device__ inline float fast_tanh(float x) {
  float e = __builtin_amdgcn_exp2f(2.885390081777927f * x);
  return 1.0f - 2.0f * __builtin_amdgcn_rcpf(e + 1.0f);
}

// MFMA with acc pinned to arch VGPRs; B operand VGPR- or AGPR-resident.
__device__ __forceinline__ void mfma_vv(float4v& acc, short8 a, short8 b) {
  asm("v_mfma_f32_16x16x32_bf16 %0, %1, %2, %0" : "+v"(acc) : "v"(a), "v"(b));
}
__device__ __forceinline__ void mfma_va(float4v& acc, short8 a, short8 b) {
  asm("v_mfma_f32_16x16x32_bf16 %0, %1, %2, %0" : "+v"(acc) : "v"(a), "a"(b));
}
#define PIN_AGPR(x) asm("" : "+a"(x))

// async global->LDS DMA, 16B per lane, LDS dest = uniform base + lane*16
__device__ __forceinline__ void async_copy16(char* lds, const char* g) {
  __builtin_amdgcn_global_load_lds(
      (const __attribute__((address_space(1))) unsigned int*)g,
      (__attribute__((address_space(3))) unsigned int*)lds, 16, 0, 0);
}

// ---------------------------------------------------------------------------
__global__ void detect(const unsigned int* __restrict__ w, int* __restrict__ flag) {
  __shared__ int bad;
  if (threadIdx.x == 0) bad = 0;
  __syncthreads();
  int local = 0;
  for (int i = threadIdx.x; i < 4096; i += 256) {
    const unsigned int x = w[i];
    if (((x >> 7) & 0xFFu) > 0x7Bu) local = 1;
  }
  if (local) atomicOr(&bad, 1);
  __syncthreads();
  if (threadIdx.x == 0) flag[0] = bad ? 1 : 0;
}

struct Ptrs { const void* p[12]; };

__global__ __launch_bounds__(256) void cvt_seg(Ptrs ps, char* __restrict__ wsb,
                                               const int* __restrict__ flag) {
  const int cnt[12] = {196608, 196608, 196608, 196608, 768, 768, 768, 768,
                       262144, 512, 5120, 10};
  const int off[12] = {(int)OFF_WIHF, (int)OFF_WHHF, (int)OFF_WIHB, (int)OFF_WHHB,
                       (int)OFF_BIHF, (int)OFF_BHHF, (int)OFF_BIHB, (int)OFF_BHHB,
                       (int)OFF_W1,   (int)OFF_B1,   (int)OFF_W2,   (int)OFF_B2};
  const int seg = blockIdx.y;
  const int n = cnt[seg];
  unsigned short* dst = (unsigned short*)(wsb + off[seg]);
  const int stride = gridDim.x * blockDim.x;
  int i = blockIdx.x * blockDim.x + threadIdx.x;
  if (flag[0]) {
    const float* s = (const float*)ps.p[seg];
    for (; i < n; i += stride) dst[i] = f2bf(s[i]);
  } else {
    const unsigned short* s = (const unsigned short*)ps.p[seg];
    for (; i < n; i += stride) dst[i] = s[i];
  }
}

__global__ __launch_bounds__(256) void cvt_emb(const void* __restrict__ src,
                                               unsigned short* __restrict__ dst,
                                               const int* __restrict__ flag) {
  const int n = 12800000;
  const int stride = gridDim.x * blockDim.x;
  int i = blockIdx.x * blockDim.x + threadIdx.x;
  if (flag[0]) {
    const float* s = (const float*)src;
    for (; i < n; i += stride) dst[i] = f2bf(s[i]);
  } else {
    const unsigned short* s = (const unsigned short*)src;
    for (; i < n; i += stride) dst[i] = s[i];
  }
}

// ---------------------------------------------------------------------------
__global__ void zerok(uint4* __restrict__ p, int n4) {
  int i = blockIdx.x * blockDim.x + threadIdx.x;
  if (i < n4) { uint4 z; z.x = z.y = z.z = z.w = 0u; p[i] = z; }
}

// ---------------------------------------------------------------------------
// gi GEMM for one chunk. fp32 out via non-temporal stores.
// grid = (6, Tc*2, 2), block = 512.
__global__ __launch_bounds__(512, 4) void gi_gemm(
    const int* __restrict__ seqs, const int* __restrict__ lens,
    const unsigned short* __restrict__ emb,
    const unsigned short* __restrict__ WihF, const unsigned short* __restrict__ WihB,
    float* __restrict__ giF, float* __restrict__ giB,
    int t0f, int t0b)
{
  const int dir = blockIdx.z;
  const int nblk = blockIdx.x;
  const int tl = blockIdx.y >> 1;
  const int bh = blockIdx.y & 1;
  const int t = (dir ? t0b : t0f) + tl;

  int lo = 0, hi = 256;
  while (lo < hi) { int mid = (lo + hi) >> 1; if (lens[mid] > t) lo = mid + 1; else hi = mid; }
  const int n1 = lo;
  lo = 0; hi = 256;
  const int thr2 = 512 - t;
  while (lo < hi) { int mid = (lo + hi) >> 1; if (lens[mid] >= thr2) lo = mid + 1; else hi = mid; }
  const int n2 = lo;
  const int nneed = n1 < n2 ? n1 : n2;
  if (nneed <= bh * 128) return;

  const unsigned short* Wih = dir ? WihB : WihF;
  float* gi = dir ? giB : giF;

  __shared__ __attribute__((aligned(16))) short lA[128 * 256];

  const int tid = threadIdx.x;
  {
    const int kb = tid & 31;
    const int m0 = tid >> 5;
#pragma unroll
    for (int it = 0; it < 8; ++it) {
      const int m = it * 16 + m0;
      const int b = bh * 128 + m;
      const int tok = seqs[b * 512 + t];
      const uint4 v = *(const uint4*)(const void*)(emb + (size_t)tok * 256 + kb * 8);
      *(uint4*)(void*)(&lA[m * 256 + ((kb ^ (m & 7)) << 3)]) = v;
    }
  }
  __syncthreads();

  const int w = tid >> 6, lane = tid & 63, q = lane >> 4, n16 = lane & 15;
  const int mrow0 = (w & 3) * 32;
  const int ncol0 = (w >> 2) * 64;

  float4v acc[2][4];
#pragma unroll
  for (int mt = 0; mt < 2; ++mt)
#pragma unroll
    for (int nt = 0; nt < 4; ++nt) { float4v z = {0.f, 0.f, 0.f, 0.f}; acc[mt][nt] = z; }

#pragma unroll
  for (int ks = 0; ks < 8; ++ks) {
    short8 a[2];
#pragma unroll
    for (int mt = 0; mt < 2; ++mt) {
      const int m = mrow0 + mt * 16 + n16;
      const int kb = (ks * 4 + q) ^ (m & 7);
      a[mt] = *(const short8*)(const void*)(&lA[m * 256 + kb * 8]);
    }
#pragma unroll
    for (int nt = 0; nt < 4; ++nt) {
      const int j = nblk * 128 + ncol0 + nt * 16 + n16;
      const short8 bfr = *(const short8*)(const void*)(Wih + (size_t)j * 256 + ks * 32 + q * 8);
#pragma unroll
      for (int mt = 0; mt < 2; ++mt)
        acc[mt][nt] = __builtin_amdgcn_mfma_f32_16x16x32_bf16(a[mt], bfr, acc[mt][nt], 0, 0, 0);
    }
  }

#pragma unroll
  for (int mt = 0; mt < 2; ++mt)
#pragma unroll
    for (int nt = 0; nt < 4; ++nt)
#pragma unroll
      for (int r = 0; r < 4; ++r) {
        const int row = mrow0 + mt * 16 + q * 4 + r;
        const int b = bh * 128 + row;
        const int j = nblk * 128 + ncol0 + nt * 16 + n16;
        __builtin_nontemporal_store(acc[mt][nt][r],
            &gi[((size_t)tl * 256 + b) * 768 + j]);
      }
}

// ---------------------------------------------------------------------------
// GRU recurrence. Batch row r lives at hB/A row 4r -> C row 4q in lane group
// q, reg 0 -> every lane owns (batch row q, col n16): all-lane epilogue.
// grid = 128 (2 dir x 64 groups of 4 batch rows), block = 256 (1 wave/SIMD).
__global__ __launch_bounds__(256, 1) void rec_step(
    const int* __restrict__ lens,
    const unsigned short* __restrict__ WhhF, const unsigned short* __restrict__ WhhB,
    const unsigned short* __restrict__ bihF, const unsigned short* __restrict__ bhhF,
    const unsigned short* __restrict__ bihB, const unsigned short* __restrict__ bhhB,
    const float* __restrict__ gi_rd, float* __restrict__ hstate,
    unsigned short* __restrict__ rep,
    int t0f, int t0b, int Tc)
{
  extern __shared__ char smem[];
  const int bid = blockIdx.x;
  const int d = bid >> 6;
  const int g4 = bid & 63;
  const int tid = threadIdx.x, w = tid >> 6, lane = tid & 63, q = lane >> 4, n16 = lane & 15;

  const unsigned short* Whh = d ? WhhB : WhhF;
  const unsigned short* bih = d ? bihB : bihF;
  const unsigned short* bhh = d ? bhhB : bhhF;
  const float* gi = gi_rd + (size_t)d * (size_t)Tc * 196608;
  const int t0 = d ? t0b : t0f;

  short* hB0 = (short*)smem;            // 8KB [16][256] swizzled
  short* hB1 = (short*)(smem + 8192);   // 8KB
  char*  giL = smem + 16384;            // 4 x GI_BUF4

  // zero hB0+hB1 (rows != 4r feed the MFMA A-tile and must stay zero)
  {
    uint4 z; z.x = z.y = z.z = z.w = 0u;
    uint4* p = (uint4*)smem;
    for (int i = tid; i < 1024; i += 256) p[i] = z;   // 16KB
  }

  // async prefetch of one gi tile (4 rows x 3072B); wave w loads row w.
  auto prefetch_gi = [&](int buf, int tl) {
    const char* srcB = (const char*)(gi + ((size_t)tl * 256 + g4 * 4) * 768);
    char* dstB = giL + buf * GI_BUF4;
#pragma unroll
    for (int i = 0; i < 3; ++i)
      async_copy16(dstB + w * GI_ROWB + i * 1024,
                   srcB + w * 3072 + i * 1024 + lane * 16);
  };

  // --- weight fragments: pair p = ct4*3+gate, wave w owns h-cols [4w..4w+4)*16
  const unsigned short* wbase = Whh + (size_t)q * 8;  // + j*256 + ks*32
  // pairs 0..3 -> VGPR file
  short8 wV[4][8];
#pragma unroll
  for (int p = 0; p < 4; ++p) {
    const int ct4 = p / 3, gate = p % 3;
    const int j = gate * 256 + (w * 4 + ct4) * 16 + n16;
#pragma unroll
    for (int ks = 0; ks < 8; ++ks)
      wV[p][ks] = *(const short8*)(const void*)(wbase + (size_t)j * 256 + ks * 32);
  }
  // pairs 4..11 -> AGPR file (pinned at init; only "a" uses below)
  short8 wA[8][8];
#pragma unroll
  for (int p8 = 0; p8 < 8; ++p8) {
    const int p = p8 + 4;
    const int ct4 = p / 3, gate = p % 3;
    const int j = gate * 256 + (w * 4 + ct4) * 16 + n16;
#pragma unroll
    for (int ks = 0; ks < 8; ++ks) {
      wA[p8][ks] = *(const short8*)(const void*)(wbase + (size_t)j * 256 + ks * 32);
      PIN_AGPR(wA[p8][ks]);
    }
  }

  float cr[4], cz[4], bin_[4], bhn_[4];
#pragma unroll
  for (int ct4 = 0; ct4 < 4; ++ct4) {
    const int j16 = (w * 4 + ct4) * 16 + n16;
    cr[ct4]   = bf2f(bih[j16])       + bf2f(bhh[j16]);
    cz[ct4]   = bf2f(bih[256 + j16]) + bf2f(bhh[256 + j16]);
    bin_[ct4] = bf2f(bih[512 + j16]);
    bhn_[ct4] = bf2f(bhh[512 + j16]);
  }

  const int mylen = lens[g4 * 4 + q];   // this lane's batch row = q
  const int row4 = 4 * q;               // hB row for this lane's batch row

  float h[4];
#pragma unroll
  for (int ct4 = 0; ct4 < 4; ++ct4) {
    const int col = (w * 4 + ct4) * 16 + n16;
    h[ct4] = hstate[d * 65536 + (g4 * 4 + q) * 256 + col];
  }

  __syncthreads();  // hB zero-init visible before data-row writes

#pragma unroll
  for (int ct4 = 0; ct4 < 4; ++ct4) {
    const int col = (w * 4 + ct4) * 16 + n16;
    const int kb = col >> 3;
    hB0[row4 * 256 + ((kb ^ (row4 & 7)) << 3) + (col & 7)] = (short)f2bf(h[ct4]);
  }
  // fill pipeline: tiles for steps 0,1,2
  for (int a = 0; a < 3; ++a) {
    const int tl = (a < Tc) ? (d ? (Tc - 1 - a) : a) : 0;
    prefetch_gi(a, tl);
  }
  __syncthreads();  // full drain once (prologue only); hB0 visible

  for (int s = 0; s < Tc; ++s) {
    const int t = t0 + (d ? (Tc - 1 - s) : s);

    // issue prefetch 3 steps ahead (clamped dummy at tail -- its target
    // buffer was last read at step s-1, already complete)
    {
      const int sa = s + 3;
      const int tla = (sa < Tc) ? (d ? (Tc - 1 - sa) : sa) : 0;
      prefetch_gi(sa & 3, tla);
    }

    // this step's gi tile -> registers (hidden under the MFMA block);
    // resident since end-of-step s-1's vmcnt wait.
    const float* grow = (const float*)(giL + (s & 3) * GI_BUF4 + q * GI_ROWB);
    float gr[4], gz[4], gn[4];
#pragma unroll
    for (int ct4 = 0; ct4 < 4; ++ct4) {
      const int col = (w * 4 + ct4) * 16 + n16;
      gr[ct4] = grow[col];
      gz[ct4] = grow[256 + col];
      gn[ct4] = grow[512 + col];
    }

    const short* hRd = (s & 1) ? hB1 : hB0;
    short* hWr = (s & 1) ? hB0 : hB1;

    float4v acc[12];
#pragma unroll
    for (int p = 0; p < 12; ++p) { float4v z = {0.f, 0.f, 0.f, 0.f}; acc[p] = z; }

#pragma unroll
    for (int ks = 0; ks < 8; ++ks) {
      const int kb = (ks * 4 + q) ^ (n16 & 7);
      const short8 a = *(const short8*)(const void*)(&hRd[n16 * 256 + kb * 8]);
#pragma unroll
      for (int p = 0; p < 4; ++p) mfma_vv(acc[p], a, wV[p][ks]);
#pragma unroll
      for (int p8 = 0; p8 < 8; ++p8) mfma_va(acc[p8 + 4], a, wA[p8][ks]);
    }

    // all-lane epilogue: this lane owns (batch row q, col n16); C row 4q is
    // in lane group q reg 0 -> acc[p][0].
    const bool act = (t < mylen);
    const bool ug  = (t >= 512 - mylen);
#pragma unroll
    for (int ct4 = 0; ct4 < 4; ++ct4) {
      const int col = (w * 4 + ct4) * 16 + n16;
      const int kb = col >> 3;
      const float grv = ug ? gr[ct4] : 0.f;
      const float gzv = ug ? gz[ct4] : 0.f;
      const float gnv = ug ? gn[ct4] : 0.f;
      const float rr = fast_sigmoid(grv + cr[ct4] + acc[ct4 * 3 + 0][0]);
      const float zz = fast_sigmoid(gzv + cz[ct4] + acc[ct4 * 3 + 1][0]);
      const float nn = fast_tanh(gnv + bin_[ct4] + rr * (acc[ct4 * 3 + 2][0] + bhn_[ct4]));
      const float hnew = zz * (h[ct4] - nn) + nn;
      h[ct4] = act ? hnew : h[ct4];
      hWr[row4 * 256 + ((kb ^ (row4 & 7)) << 3) + (col & 7)] = (short)f2bf(h[ct4]);
    }

    // ONE barrier/step: drains hWr writes (lgkm) and enforces that the gi
    // tile for step s+1 (issued at s-2) has landed (vmcnt(6) keeps only the
    // 6 loads from steps s-1,s in flight).
    asm volatile("s_waitcnt vmcnt(6) lgkmcnt(0)" ::: "memory");
    __builtin_amdgcn_s_barrier();
  }

#pragma unroll
  for (int ct4 = 0; ct4 < 4; ++ct4) {
    const int col = (w * 4 + ct4) * 16 + n16;
    const int b = g4 * 4 + q;
    hstate[d * 65536 + b * 256 + col] = h[ct4];
    rep[b * 512 + d * 256 + col] = f2bf(h[ct4]);
  }
}

// ---------------------------------------------------------------------------
__global__ __launch_bounds__(256, 4) void head1(
    const unsigned short* __restrict__ rep, const unsigned short* __restrict__ W1,
    const unsigned short* __restrict__ b1, unsigned short* __restrict__ hid)
{
  const int mt = blockIdx.x;
  const int nh = blockIdx.y;
  const int tid = threadIdx.x, w = tid >> 6, lane = tid & 63, q = lane >> 4, n16 = lane & 15;

  float4v acc[4];
#pragma unroll
  for (int nt = 0; nt < 4; ++nt) { float4v z = {0.f, 0.f, 0.f, 0.f}; acc[nt] = z; }

#pragma unroll
  for (int ks = 0; ks < 16; ++ks) {
    const short8 a = *(const short8*)(const void*)(rep + (size_t)(mt * 16 + n16) * 512 + ks * 32 + q * 8);
#pragma unroll
    for (int nt = 0; nt < 4; ++nt) {
      const int n = nh * 256 + w * 64 + nt * 16 + n16;
      const short8 bfr = *(const short8*)(const void*)(W1 + (size_t)n * 512 + ks * 32 + q * 8);
      acc[nt] = __builtin_amdgcn_mfma_f32_16x16x32_bf16(a, bfr, acc[nt], 0, 0, 0);
    }
  }
#pragma unroll
  for (int nt = 0; nt < 4; ++nt)
#pragma unroll
    for (int r = 0; r < 4; ++r) {
      const int row = mt * 16 + q * 4 + r;
      const int col = nh * 256 + w * 64 + nt * 16 + n16;
      hid[row * 512 + col] = f2bf(fast_tanh(acc[nt][r] + bf2f(b1[col])));
    }
}

// ---------------------------------------------------------------------------
__global__ __launch_bounds__(64, 4) void head2(
    const unsigned short* __restrict__ hid, const unsigned short* __restrict__ W2,
    const unsigned short* __restrict__ b2, void* __restrict__ out,
    const int* __restrict__ flag)
{
  const int row = blockIdx.x;
  const int lane = threadIdx.x;
  const uint4 hv = *(const uint4*)(const void*)(hid + (size_t)row * 512 + lane * 8);
  const unsigned int hu[4] = {hv.x, hv.y, hv.z, hv.w};

  float logit[10];
#pragma unroll
  for (int j = 0; j < 10; ++j) {
    const uint4 wv = *(const uint4*)(const void*)(W2 + (size_t)j * 512 + lane * 8);
    const unsigned int wu[4] = {wv.x, wv.y, wv.z, wv.w};
    float s = 0.f;
#pragma unroll
    for (int i = 0; i < 4; ++i) {
      s = fmaf(asf(hu[i] << 16), asf(wu[i] << 16), s);
      s = fmaf(asf(hu[i] & 0xffff0000u), asf(wu[i] & 0xffff0000u), s);
    }
#pragma unroll
    for (int off = 32; off > 0; off >>= 1) s += __shfl_xor(s, off);
    logit[j] = s + bf2f(b2[j]);
  }
  float mx = logit[0];
#pragma unroll
  for (int j = 1; j < 10; ++j) mx = fmaxf(mx, logit[j]);
  float e[10]; float sum = 0.f;
#pragma unroll
  for (int j = 0; j < 10; ++j) { e[j] = __builtin_amdgcn_exp2f(1.442695040888963f * (logit[j] - mx)); sum += e[j]; }
  const float rs = __builtin_amdgcn_rcpf(sum);
  if (lane < 10) {
    float p = e[0];
#pragma unroll
    for (int j = 1; j < 10; ++j) p = (lane == j) ? e[j] : p;
    if (flag[0]) ((float*)out)[row * 10 + lane] = p * rs;
    else         ((unsigned short*)out)[row * 10 + lane] = f2bf(p * rs);
  }
}

// ---------------------------------------------------------------------------
extern "C" void kernel_launch(void* const* d_in, const int* in_sizes, int n_in,
                              void* d_out, int out_size, void* d_ws, size_t ws_size,
                              hipStream_t stream)
{
  (void)in_sizes; (void)n_in; (void)out_size;
  const int* seqs = (const int*)d_in[0];
  const int* lens = (const int*)d_in[1];
  char* ws = (char*)d_ws;

  // one-time: allow >64KB dynamic LDS for rec_step (host-side, capture-safe)
  static bool s_attr_done = false;
  if (!s_attr_done) {
    (void)hipFuncSetAttribute(reinterpret_cast<const void*>(rec_step),
                              hipFuncAttributeMaxDynamicSharedMemorySize, REC_LDS);
    s_attr_done = true;
  }

  int* flag = (int*)(ws + OFF_FLAG);
  float* hstate = (float*)(ws + OFF_HST);
  unsigned short* rep  = (unsigned short*)(ws + OFF_REP);
  unsigned short* hid  = (unsigned short*)(ws + OFF_HID);
  unsigned short* WihF = (unsigned short*)(ws + OFF_WIHF);
  unsigned short* WhhF = (unsigned short*)(ws + OFF_WHHF);
  unsigned short* WihB = (unsigned short*)(ws + OFF_WIHB);
  unsigned short* WhhB = (unsigned short*)(ws + OFF_WHHB);
  unsigned short* bihF = (unsigned short*)(ws + OFF_BIHF);
  unsigned short* bhhF = (unsigned short*)(ws + OFF_BHHF);
  unsigned short* bihB = (unsigned short*)(ws + OFF_BIHB);
  unsigned short* bhhB = (unsigned short*)(ws + OFF_BHHB);
  unsigned short* W1C  = (unsigned short*)(ws + OFF_W1);
  unsigned short* b1C  = (unsigned short*)(ws + OFF_B1);
  unsigned short* W2C  = (unsigned short*)(ws + OFF_W2);
  unsigned short* b2C  = (unsigned short*)(ws + OFF_B2);
  unsigned short* embC = (unsigned short*)(ws + OFF_EMB);

  detect<<<1, 256, 0, stream>>>((const unsigned int*)d_in[4], flag);
  Ptrs ps;
  ps.p[0] = d_in[3];  ps.p[1] = d_in[4];  ps.p[2] = d_in[7];  ps.p[3] = d_in[8];
  ps.p[4] = d_in[5];  ps.p[5] = d_in[6];  ps.p[6] = d_in[9];  ps.p[7] = d_in[10];
  ps.p[8] = d_in[11]; ps.p[9] = d_in[12]; ps.p[10] = d_in[13]; ps.p[11] = d_in[14];
  cvt_seg<<<dim3(64, 12), 256, 0, stream>>>(ps, ws, flag);
  cvt_emb<<<2048, 256, 0, stream>>>(d_in[2], embC, flag);

  zerok<<<128, 256, 0, stream>>>((uint4*)hstate, 32768);

  // Tc: ping-pong fp32 gi needs OFF_GI + 4*Tc*786432 bytes
  int Tc = 4;
  const int cands[4] = {32, 16, 8, 4};
  for (int i = 0; i < 4; ++i) {
    if (OFF_GI + 4ull * (size_t)cands[i] * 786432ull <= ws_size) { Tc = cands[i]; break; }
  }
  float* gi0 = (float*)(ws + OFF_GI);
  float* gi1 = gi0 + 2ull * (size_t)Tc * 196608ull;

  // prologue: chunk 0 into gi0
  gi_gemm<<<dim3(6, Tc * 2, 2), 512, 0, stream>>>(seqs, lens, embC, WihF, WihB,
      gi0, gi0 + (size_t)Tc * 196608ull, 0, 512 - Tc);

  const int NC = 512 / Tc;
  for (int c = 0; c < NC; ++c) {
    float* rd = (c & 1) ? gi1 : gi0;
    float* wr = (c & 1) ? gi0 : gi1;
    rec_step<<<128, 256, REC_LDS, stream>>>(lens, WhhF, WhhB,
        bihF, bhhF, bihB, bhhB, rd, hstate, rep,
        c * Tc, 512 - (c + 1) * Tc, Tc);
    if (c + 1 < NC) {
      gi_gemm<<<dim3(6, Tc * 2, 2), 512, 0, stream>>>(seqs, lens, embC, WihF, WihB,
          wr, wr + (size_t)Tc * 196608ull, (c + 1) * Tc, 512 - (c + 2) * Tc);
    }
  }
  head1<<<dim3(16, 2), 256, 0, stream>>>(rep, W1C, b1C, hid);
  head2<<<256, 64, 0, stream>>>(hid, W2C, b2C, d_out, flag);
}

// Round 9
// 1107.555 us; speedup vs baseline: 2.4716x; 1.3681x over previous
//
#include <hip/hip_runtime.h>
#include <hip/hip_bf16.h>
#include <stdint.h>

// ---------------------------------------------------------------------------
// EncoderRNN: embedding-gather + bidirectional GRU (T=512,B=256,H=E=256) +
// tanh FC (512->512) + softmax FC (512->10).
//
// R13: R12 fixed the serial epilogue (step 4.1 -> 1.78us, rec 57us/chunk).
// Remaining ~550us = serialized gi_gemm (~35us x 15) while 128 CUs idle
// under rec. Fix: re-fuse (R9 pattern) -- blocks 0..127 = rec chunk c
// (R12 code byte-identical), blocks 128.. = gemm chunk c+1 on idle CUs,
// hidden under rec's 57us. Gemm role N=128/block (6 nblk, acc[2][8]=64
// VGPR) halving R9's 12x emb-gather redundancy. Weight recipe unchanged
// (wV 4 pairs VGPR / wA 8 pairs AGPR, VGPR=256, launch_bounds(256,1)).
// ---------------------------------------------------------------------------

using short8  = __attribute__((ext_vector_type(8))) short;
using float4v = __attribute__((ext_vector_type(4))) float;

// ws layout (bytes)
constexpr size_t OFF_FLAG = 0;
constexpr size_t OFF_HST  = 64;                      // fp32 [2][256][256]
constexpr size_t OFF_REP  = OFF_HST  + 524288;       // bf16 [256][512]
constexpr size_t OFF_HID  = OFF_REP  + 262144;       // bf16 [256][512]
constexpr size_t OFF_WIHF = OFF_HID  + 262144;       // bf16 [768][256]
constexpr size_t OFF_WHHF = OFF_WIHF + 393216;
constexpr size_t OFF_WIHB = OFF_WHHF + 393216;
constexpr size_t OFF_WHHB = OFF_WIHB + 393216;
constexpr size_t OFF_BIHF = OFF_WHHB + 393216;       // bf16 [768]
constexpr size_t OFF_BHHF = OFF_BIHF + 1536;
constexpr size_t OFF_BIHB = OFF_BHHF + 1536;
constexpr size_t OFF_BHHB = OFF_BIHB + 1536;
constexpr size_t OFF_W1   = OFF_BHHB + 1536;         // bf16 [512][512]
constexpr size_t OFF_B1   = OFF_W1   + 524288;       // bf16 [512]
constexpr size_t OFF_W2   = OFF_B1   + 1024;         // bf16 [10][512]
constexpr size_t OFF_B2   = OFF_W2   + 10240;        // bf16 [10]
constexpr size_t OFF_EMB  = OFF_B2   + 64;           // bf16 [50000][256]
constexpr size_t OFF_GI   = OFF_EMB  + 25600000;     // fp32 gi ping-pong

// rec gi LDS: 4 rows x 3088B per buffer, 4 buffers (3-ahead pipeline)
constexpr int GI_ROWB = 3088;                        // 772 dw (2-way banks)
constexpr int GI_BUF4 = 4 * GI_ROWB;                 // 12352
constexpr int FUS_LDS = 16384 + 4 * GI_BUF4;         // 65792 (gemm lA=64K fits)

__device__ inline float asf(unsigned int u) {
  union { unsigned int i; float f; } v; v.i = u; return v.f;
}
__device__ inline float bf2f(unsigned short u) {
  return asf(((unsigned int)u) << 16);
}
__device__ inline unsigned short f2bf(float f) {
  union { float f; unsigned int i; } v; v.f = f;
  unsigned int i = v.i;
  return (unsigned short)((i + 0x7FFFu + ((i >> 16) & 1u)) >> 16);  // RNE
}
__device__ inline float fast_sigmoid(float x) {
  float e = __builtin_amdgcn_exp2f(-1.442695040888963f * x);
  return __builtin_amdgcn_rcpf(1.0f + e);
}
__device__ inline float fast_tanh(float x) {
  float e = __builtin_amdgcn_exp2f(2.885390081777927f * x);
  return 1.0f - 2.0f * __builtin_amdgcn_rcpf(e + 1.0f);
}

// MFMA with acc pinned to arch VGPRs; B operand VGPR- or AGPR-resident.
__device__ __forceinline__ void mfma_vv(float4v& acc, short8 a, short8 b) {
  asm("v_mfma_f32_16x16x32_bf16 %0, %1, %2, %0" : "+v"(acc) : "v"(a), "v"(b));
}
__device__ __forceinline__ void mfma_va(float4v& acc, short8 a, short8 b) {
  asm("v_mfma_f32_16x16x32_bf16 %0, %1, %2, %0" : "+v"(acc) : "v"(a), "a"(b));
}
#define PIN_AGPR(x) asm("" : "+a"(x))

// async global->LDS DMA, 16B per lane, LDS dest = uniform base + lane*16
__device__ __forceinline__ void async_copy16(char* lds, const char* g) {
  __builtin_amdgcn_global_load_lds(
      (const __attribute__((address_space(1))) unsigned int*)g,
      (__attribute__((address_space(3))) unsigned int*)lds, 16, 0, 0);
}

// ---------------------------------------------------------------------------
__global__ void detect(const unsigned int* __restrict__ w, int* __restrict__ flag) {
  __shared__ int bad;
  if (threadIdx.x == 0) bad = 0;
  __syncthreads();
  int local = 0;
  for (int i = threadIdx.x; i < 4096; i += 256) {
    const unsigned int x = w[i];
    if (((x >> 7) & 0xFFu) > 0x7Bu) local = 1;
  }
  if (local) atomicOr(&bad, 1);
  __syncthreads();
  if (threadIdx.x == 0) flag[0] = bad ? 1 : 0;
}

struct Ptrs { const void* p[12]; };

__global__ __launch_bounds__(256) void cvt_seg(Ptrs ps, char* __restrict__ wsb,
                                               const int* __restrict__ flag) {
  const int cnt[12] = {196608, 196608, 196608, 196608, 768, 768, 768, 768,
                       262144, 512, 5120, 10};
  const int off[12] = {(int)OFF_WIHF, (int)OFF_WHHF, (int)OFF_WIHB, (int)OFF_WHHB,
                       (int)OFF_BIHF, (int)OFF_BHHF, (int)OFF_BIHB, (int)OFF_BHHB,
                       (int)OFF_W1,   (int)OFF_B1,   (int)OFF_W2,   (int)OFF_B2};
  const int seg = blockIdx.y;
  const int n = cnt[seg];
  unsigned short* dst = (unsigned short*)(wsb + off[seg]);
  const int stride = gridDim.x * blockDim.x;
  int i = blockIdx.x * blockDim.x + threadIdx.x;
  if (flag[0]) {
    const float* s = (const float*)ps.p[seg];
    for (; i < n; i += stride) dst[i] = f2bf(s[i]);
  } else {
    const unsigned short* s = (const unsigned short*)ps.p[seg];
    for (; i < n; i += stride) dst[i] = s[i];
  }
}

__global__ __launch_bounds__(256) void cvt_emb(const void* __restrict__ src,
                                               unsigned short* __restrict__ dst,
                                               const int* __restrict__ flag) {
  const int n = 12800000;
  const int stride = gridDim.x * blockDim.x;
  int i = blockIdx.x * blockDim.x + threadIdx.x;
  if (flag[0]) {
    const float* s = (const float*)src;
    for (; i < n; i += stride) dst[i] = f2bf(s[i]);
  } else {
    const unsigned short* s = (const unsigned short*)src;
    for (; i < n; i += stride) dst[i] = s[i];
  }
}

// ---------------------------------------------------------------------------
__global__ void zerok(uint4* __restrict__ p, int n4) {
  int i = blockIdx.x * blockDim.x + threadIdx.x;
  if (i < n4) { uint4 z; z.x = z.y = z.z = z.w = 0u; p[i] = z; }
}

// ---------------------------------------------------------------------------
// standalone gi GEMM (prologue, chunk 0). fp32 out via nt stores.
// grid = (6, Tc*2, 2), block = 512.
__global__ __launch_bounds__(512, 4) void gi_gemm(
    const int* __restrict__ seqs, const int* __restrict__ lens,
    const unsigned short* __restrict__ emb,
    const unsigned short* __restrict__ WihF, const unsigned short* __restrict__ WihB,
    float* __restrict__ giF, float* __restrict__ giB,
    int t0f, int t0b)
{
  const int dir = blockIdx.z;
  const int nblk = blockIdx.x;
  const int tl = blockIdx.y >> 1;
  const int bh = blockIdx.y & 1;
  const int t = (dir ? t0b : t0f) + tl;

  int lo = 0, hi = 256;
  while (lo < hi) { int mid = (lo + hi) >> 1; if (lens[mid] > t) lo = mid + 1; else hi = mid; }
  const int n1 = lo;
  lo = 0; hi = 256;
  const int thr2 = 512 - t;
  while (lo < hi) { int mid = (lo + hi) >> 1; if (lens[mid] >= thr2) lo = mid + 1; else hi = mid; }
  const int n2 = lo;
  const int nneed = n1 < n2 ? n1 : n2;
  if (nneed <= bh * 128) return;

  const unsigned short* Wih = dir ? WihB : WihF;
  float* gi = dir ? giB : giF;

  __shared__ __attribute__((aligned(16))) short lA[128 * 256];

  const int tid = threadIdx.x;
  {
    const int kb = tid & 31;
    const int m0 = tid >> 5;
#pragma unroll
    for (int it = 0; it < 8; ++it) {
      const int m = it * 16 + m0;
      const int b = bh * 128 + m;
      const int tok = seqs[b * 512 + t];
      const uint4 v = *(const uint4*)(const void*)(emb + (size_t)tok * 256 + kb * 8);
      *(uint4*)(void*)(&lA[m * 256 + ((kb ^ (m & 7)) << 3)]) = v;
    }
  }
  __syncthreads();

  const int w = tid >> 6, lane = tid & 63, q = lane >> 4, n16 = lane & 15;
  const int mrow0 = (w & 3) * 32;
  const int ncol0 = (w >> 2) * 64;

  float4v acc[2][4];
#pragma unroll
  for (int mt = 0; mt < 2; ++mt)
#pragma unroll
    for (int nt = 0; nt < 4; ++nt) { float4v z = {0.f, 0.f, 0.f, 0.f}; acc[mt][nt] = z; }

#pragma unroll
  for (int ks = 0; ks < 8; ++ks) {
    short8 a[2];
#pragma unroll
    for (int mt = 0; mt < 2; ++mt) {
      const int m = mrow0 + mt * 16 + n16;
      const int kb = (ks * 4 + q) ^ (m & 7);
      a[mt] = *(const short8*)(const void*)(&lA[m * 256 + kb * 8]);
    }
#pragma unroll
    for (int nt = 0; nt < 4; ++nt) {
      const int j = nblk * 128 + ncol0 + nt * 16 + n16;
      const short8 bfr = *(const short8*)(const void*)(Wih + (size_t)j * 256 + ks * 32 + q * 8);
#pragma unroll
      for (int mt = 0; mt < 2; ++mt)
        acc[mt][nt] = __builtin_amdgcn_mfma_f32_16x16x32_bf16(a[mt], bfr, acc[mt][nt], 0, 0, 0);
    }
  }

#pragma unroll
  for (int mt = 0; mt < 2; ++mt)
#pragma unroll
    for (int nt = 0; nt < 4; ++nt)
#pragma unroll
      for (int r = 0; r < 4; ++r) {
        const int row = mrow0 + mt * 16 + q * 4 + r;
        const int b = bh * 128 + row;
        const int j = nblk * 128 + ncol0 + nt * 16 + n16;
        __builtin_nontemporal_store(acc[mt][nt][r],
            &gi[((size_t)tl * 256 + b) * 768 + j]);
      }
}

// ---------------------------------------------------------------------------
// Fused: blocks 0..127 = GRU recurrence chunk c (R12 code, byte-identical);
//        blocks 128..128+24*Tc-1 = gi GEMM chunk c+1 (M=128 x N=128 tiles).
// block = 256, dynamic LDS = FUS_LDS, launch_bounds(256,1) -> 512-reg budget.
__global__ __launch_bounds__(256, 1) void fused_step(
    const int* __restrict__ seqs, const int* __restrict__ lens,
    const unsigned short* __restrict__ emb,
    const unsigned short* __restrict__ WihF, const unsigned short* __restrict__ WihB,
    const unsigned short* __restrict__ WhhF, const unsigned short* __restrict__ WhhB,
    const unsigned short* __restrict__ bihF, const unsigned short* __restrict__ bhhF,
    const unsigned short* __restrict__ bihB, const unsigned short* __restrict__ bhhB,
    const float* __restrict__ gi_rd, float* __restrict__ gi_wr,
    float* __restrict__ hstate, unsigned short* __restrict__ rep,
    int t0f, int t0b, int t0f_g, int t0b_g, int Tc, int do_gemm)
{
  extern __shared__ char smem[];
  const int bid = blockIdx.x;
  const int tid = threadIdx.x, w = tid >> 6, lane = tid & 63, q = lane >> 4, n16 = lane & 15;

  if (bid < 128) {
    // ------------------------- recurrence (chunk c) -------------------------
    const int d = bid >> 6;
    const int g4 = bid & 63;

    const unsigned short* Whh = d ? WhhB : WhhF;
    const unsigned short* bih = d ? bihB : bihF;
    const unsigned short* bhh = d ? bhhB : bhhF;
    const float* gi = gi_rd + (size_t)d * (size_t)Tc * 196608;
    const int t0 = d ? t0b : t0f;

    short* hB0 = (short*)smem;            // 8KB [16][256] swizzled
    short* hB1 = (short*)(smem + 8192);   // 8KB
    char*  giL = smem + 16384;            // 4 x GI_BUF4

    // zero hB0+hB1 (rows != 4r feed the MFMA A-tile and must stay zero)
    {
      uint4 z; z.x = z.y = z.z = z.w = 0u;
      uint4* p = (uint4*)smem;
      for (int i = tid; i < 1024; i += 256) p[i] = z;   // 16KB
    }

    // async prefetch of one gi tile (4 rows x 3072B); wave w loads row w.
    auto prefetch_gi = [&](int buf, int tl) {
      const char* srcB = (const char*)(gi + ((size_t)tl * 256 + g4 * 4) * 768);
      char* dstB = giL + buf * GI_BUF4;
#pragma unroll
      for (int i = 0; i < 3; ++i)
        async_copy16(dstB + w * GI_ROWB + i * 1024,
                     srcB + w * 3072 + i * 1024 + lane * 16);
    };

    // --- weight fragments: pair p = ct4*3+gate, wave w owns h-cols [4w..4w+4)*16
    const unsigned short* wbase = Whh + (size_t)q * 8;  // + j*256 + ks*32
    // pairs 0..3 -> VGPR file
    short8 wV[4][8];
#pragma unroll
    for (int p = 0; p < 4; ++p) {
      const int ct4 = p / 3, gate = p % 3;
      const int j = gate * 256 + (w * 4 + ct4) * 16 + n16;
#pragma unroll
      for (int ks = 0; ks < 8; ++ks)
        wV[p][ks] = *(const short8*)(const void*)(wbase + (size_t)j * 256 + ks * 32);
    }
    // pairs 4..11 -> AGPR file (pinned at init; only "a" uses below)
    short8 wA[8][8];
#pragma unroll
    for (int p8 = 0; p8 < 8; ++p8) {
      const int p = p8 + 4;
      const int ct4 = p / 3, gate = p % 3;
      const int j = gate * 256 + (w * 4 + ct4) * 16 + n16;
#pragma unroll
      for (int ks = 0; ks < 8; ++ks) {
        wA[p8][ks] = *(const short8*)(const void*)(wbase + (size_t)j * 256 + ks * 32);
        PIN_AGPR(wA[p8][ks]);
      }
    }

    float cr[4], cz[4], bin_[4], bhn_[4];
#pragma unroll
    for (int ct4 = 0; ct4 < 4; ++ct4) {
      const int j16 = (w * 4 + ct4) * 16 + n16;
      cr[ct4]   = bf2f(bih[j16])       + bf2f(bhh[j16]);
      cz[ct4]   = bf2f(bih[256 + j16]) + bf2f(bhh[256 + j16]);
      bin_[ct4] = bf2f(bih[512 + j16]);
      bhn_[ct4] = bf2f(bhh[512 + j16]);
    }

    const int mylen = lens[g4 * 4 + q];   // this lane's batch row = q
    const int row4 = 4 * q;               // hB row for this lane's batch row

    float h[4];
#pragma unroll
    for (int ct4 = 0; ct4 < 4; ++ct4) {
      const int col = (w * 4 + ct4) * 16 + n16;
      h[ct4] = hstate[d * 65536 + (g4 * 4 + q) * 256 + col];
    }

    __syncthreads();  // hB zero-init visible before data-row writes

#pragma unroll
    for (int ct4 = 0; ct4 < 4; ++ct4) {
      const int col = (w * 4 + ct4) * 16 + n16;
      const int kb = col >> 3;
      hB0[row4 * 256 + ((kb ^ (row4 & 7)) << 3) + (col & 7)] = (short)f2bf(h[ct4]);
    }
    // fill pipeline: tiles for steps 0,1,2
    for (int a = 0; a < 3; ++a) {
      const int tl = (a < Tc) ? (d ? (Tc - 1 - a) : a) : 0;
      prefetch_gi(a, tl);
    }
    __syncthreads();  // full drain once (prologue only); hB0 visible

    for (int s = 0; s < Tc; ++s) {
      const int t = t0 + (d ? (Tc - 1 - s) : s);

      // issue prefetch 3 steps ahead (clamped dummy at tail)
      {
        const int sa = s + 3;
        const int tla = (sa < Tc) ? (d ? (Tc - 1 - sa) : sa) : 0;
        prefetch_gi(sa & 3, tla);
      }

      // this step's gi tile -> registers (hidden under the MFMA block)
      const float* grow = (const float*)(giL + (s & 3) * GI_BUF4 + q * GI_ROWB);
      float gr[4], gz[4], gn[4];
#pragma unroll
      for (int ct4 = 0; ct4 < 4; ++ct4) {
        const int col = (w * 4 + ct4) * 16 + n16;
        gr[ct4] = grow[col];
        gz[ct4] = grow[256 + col];
        gn[ct4] = grow[512 + col];
      }

      const short* hRd = (s & 1) ? hB1 : hB0;
      short* hWr = (s & 1) ? hB0 : hB1;

      float4v acc[12];
#pragma unroll
      for (int p = 0; p < 12; ++p) { float4v z = {0.f, 0.f, 0.f, 0.f}; acc[p] = z; }

#pragma unroll
      for (int ks = 0; ks < 8; ++ks) {
        const int kb = (ks * 4 + q) ^ (n16 & 7);
        const short8 a = *(const short8*)(const void*)(&hRd[n16 * 256 + kb * 8]);
#pragma unroll
        for (int p = 0; p < 4; ++p) mfma_vv(acc[p], a, wV[p][ks]);
#pragma unroll
        for (int p8 = 0; p8 < 8; ++p8) mfma_va(acc[p8 + 4], a, wA[p8][ks]);
      }

      // all-lane epilogue: lane owns (batch row q, col n16); C row 4q -> reg 0
      const bool act = (t < mylen);
      const bool ug  = (t >= 512 - mylen);
#pragma unroll
      for (int ct4 = 0; ct4 < 4; ++ct4) {
        const int col = (w * 4 + ct4) * 16 + n16;
        const int kb = col >> 3;
        const float grv = ug ? gr[ct4] : 0.f;
        const float gzv = ug ? gz[ct4] : 0.f;
        const float gnv = ug ? gn[ct4] : 0.f;
        const float rr = fast_sigmoid(grv + cr[ct4] + acc[ct4 * 3 + 0][0]);
        const float zz = fast_sigmoid(gzv + cz[ct4] + acc[ct4 * 3 + 1][0]);
        const float nn = fast_tanh(gnv + bin_[ct4] + rr * (acc[ct4 * 3 + 2][0] + bhn_[ct4]));
        const float hnew = zz * (h[ct4] - nn) + nn;
        h[ct4] = act ? hnew : h[ct4];
        hWr[row4 * 256 + ((kb ^ (row4 & 7)) << 3) + (col & 7)] = (short)f2bf(h[ct4]);
      }

      // ONE barrier/step: drains hWr (lgkm) + gi tile for s+1 (vmcnt(6) keeps
      // only the 6 loads from steps s-1,s in flight).
      asm volatile("s_waitcnt vmcnt(6) lgkmcnt(0)" ::: "memory");
      __builtin_amdgcn_s_barrier();
    }

#pragma unroll
    for (int ct4 = 0; ct4 < 4; ++ct4) {
      const int col = (w * 4 + ct4) * 16 + n16;
      const int b = g4 * 4 + q;
      hstate[d * 65536 + b * 256 + col] = h[ct4];
      rep[b * 512 + d * 256 + col] = f2bf(h[ct4]);
    }
    return;
  }

  // ------------------------- gi GEMM (chunk c+1) -------------------------
  if (!do_gemm) return;
  const int g2 = bid - 128;
  const int nblk = g2 % 6;              // N-block of 128 gate-cols
  const int rest = g2 / 6;
  const int yy = rest % (2 * Tc);
  const int dirg = rest / (2 * Tc);
  const int tl = yy >> 1;
  const int bh = yy & 1;
  const int t = (dirg ? t0b_g : t0f_g) + tl;

  int lo = 0, hi = 256;
  while (lo < hi) { int mid = (lo + hi) >> 1; if (lens[mid] > t) lo = mid + 1; else hi = mid; }
  const int n1 = lo;
  lo = 0; hi = 256;
  const int thr2 = 512 - t;
  while (lo < hi) { int mid = (lo + hi) >> 1; if (lens[mid] >= thr2) lo = mid + 1; else hi = mid; }
  const int n2 = lo;
  const int nneed = n1 < n2 ? n1 : n2;
  if (nneed <= bh * 128) return;

  const unsigned short* Wih = dirg ? WihB : WihF;
  float* gi = gi_wr + (size_t)dirg * (size_t)Tc * 196608;

  short* lA = (short*)smem;  // 64KB [128][256] swizzled

  {
    const int kb = tid & 31;
    const int m0 = tid >> 5;  // 0..7
#pragma unroll
    for (int it = 0; it < 16; ++it) {
      const int m = it * 8 + m0;
      const int b = bh * 128 + m;
      const int tok = seqs[b * 512 + t];
      const uint4 v = *(const uint4*)(const void*)(emb + (size_t)tok * 256 + kb * 8);
      *(uint4*)(void*)(&lA[m * 256 + ((kb ^ (m & 7)) << 3)]) = v;
    }
  }
  __syncthreads();

  const int mrow0 = w * 32;

  float4v acc[2][8];
#pragma unroll
  for (int mt = 0; mt < 2; ++mt)
#pragma unroll
    for (int nt = 0; nt < 8; ++nt) { float4v z = {0.f, 0.f, 0.f, 0.f}; acc[mt][nt] = z; }

#pragma unroll
  for (int ks = 0; ks < 8; ++ks) {
    short8 a[2];
#pragma unroll
    for (int mt = 0; mt < 2; ++mt) {
      const int m = mrow0 + mt * 16 + n16;
      const int kb = (ks * 4 + q) ^ (m & 7);
      a[mt] = *(const short8*)(const void*)(&lA[m * 256 + kb * 8]);
    }
#pragma unroll
    for (int nt = 0; nt < 8; ++nt) {
      const int j = nblk * 128 + nt * 16 + n16;
      const short8 bfr = *(const short8*)(const void*)(Wih + (size_t)j * 256 + ks * 32 + q * 8);
#pragma unroll
      for (int mt = 0; mt < 2; ++mt)
        acc[mt][nt] = __builtin_amdgcn_mfma_f32_16x16x32_bf16(a[mt], bfr, acc[mt][nt], 0, 0, 0);
    }
  }

#pragma unroll
  for (int mt = 0; mt < 2; ++mt)
#pragma unroll
    for (int nt = 0; nt < 8; ++nt)
#pragma unroll
      for (int r = 0; r < 4; ++r) {
        const int row = mrow0 + mt * 16 + q * 4 + r;
        const int b = bh * 128 + row;
        const int j = nblk * 128 + nt * 16 + n16;
        __builtin_nontemporal_store(acc[mt][nt][r],
            &gi[((size_t)tl * 256 + b) * 768 + j]);
      }
}

// ---------------------------------------------------------------------------
__global__ __launch_bounds__(256, 4) void head1(
    const unsigned short* __restrict__ rep, const unsigned short* __restrict__ W1,
    const unsigned short* __restrict__ b1, unsigned short* __restrict__ hid)
{
  const int mt = blockIdx.x;
  const int nh = blockIdx.y;
  const int tid = threadIdx.x, w = tid >> 6, lane = tid & 63, q = lane >> 4, n16 = lane & 15;

  float4v acc[4];
#pragma unroll
  for (int nt = 0; nt < 4; ++nt) { float4v z = {0.f, 0.f, 0.f, 0.f}; acc[nt] = z; }

#pragma unroll
  for (int ks = 0; ks < 16; ++ks) {
    const short8 a = *(const short8*)(const void*)(rep + (size_t)(mt * 16 + n16) * 512 + ks * 32 + q * 8);
#pragma unroll
    for (int nt = 0; nt < 4; ++nt) {
      const int n = nh * 256 + w * 64 + nt * 16 + n16;
      const short8 bfr = *(const short8*)(const void*)(W1 + (size_t)n * 512 + ks * 32 + q * 8);
      acc[nt] = __builtin_amdgcn_mfma_f32_16x16x32_bf16(a, bfr, acc[nt], 0, 0, 0);
    }
  }
#pragma unroll
  for (int nt = 0; nt < 4; ++nt)
#pragma unroll
    for (int r = 0; r < 4; ++r) {
      const int row = mt * 16 + q * 4 + r;
      const int col = nh * 256 + w * 64 + nt * 16 + n16;
      hid[row * 512 + col] = f2bf(fast_tanh(acc[nt][r] + bf2f(b1[col])));
    }
}

// ---------------------------------------------------------------------------
__global__ __launch_bounds__(64, 4) void head2(
    const unsigned short* __restrict__ hid, const unsigned short* __restrict__ W2,
    const unsigned short* __restrict__ b2, void* __restrict__ out,
    const int* __restrict__ flag)
{
  const int row = blockIdx.x;
  const int lane = threadIdx.x;
  const uint4 hv = *(const uint4*)(const void*)(hid + (size_t)row * 512 + lane * 8);
  const unsigned int hu[4] = {hv.x, hv.y, hv.z, hv.w};

  float logit[10];
#pragma unroll
  for (int j = 0; j < 10; ++j) {
    const uint4 wv = *(const uint4*)(const void*)(W2 + (size_t)j * 512 + lane * 8);
    const unsigned int wu[4] = {wv.x, wv.y, wv.z, wv.w};
    float s = 0.f;
#pragma unroll
    for (int i = 0; i < 4; ++i) {
      s = fmaf(asf(hu[i] << 16), asf(wu[i] << 16), s);
      s = fmaf(asf(hu[i] & 0xffff0000u), asf(wu[i] & 0xffff0000u), s);
    }
#pragma unroll
    for (int off = 32; off > 0; off >>= 1) s += __shfl_xor(s, off);
    logit[j] = s + bf2f(b2[j]);
  }
  float mx = logit[0];
#pragma unroll
  for (int j = 1; j < 10; ++j) mx = fmaxf(mx, logit[j]);
  float e[10]; float sum = 0.f;
#pragma unroll
  for (int j = 0; j < 10; ++j) { e[j] = __builtin_amdgcn_exp2f(1.442695040888963f * (logit[j] - mx)); sum += e[j]; }
  const float rs = __builtin_amdgcn_rcpf(sum);
  if (lane < 10) {
    float p = e[0];
#pragma unroll
    for (int j = 1; j < 10; ++j) p = (lane == j) ? e[j] : p;
    if (flag[0]) ((float*)out)[row * 10 + lane] = p * rs;
    else         ((unsigned short*)out)[row * 10 + lane] = f2bf(p * rs);
  }
}

// ---------------------------------------------------------------------------
extern "C" void kernel_launch(void* const* d_in, const int* in_sizes, int n_in,
                              void* d_out, int out_size, void* d_ws, size_t ws_size,
                              hipStream_t stream)
{
  (void)in_sizes; (void)n_in; (void)out_size;
  const int* seqs = (const int*)d_in[0];
  const int* lens = (const int*)d_in[1];
  char* ws = (char*)d_ws;

  // one-time: allow >64KB dynamic LDS for fused_step (host-side, capture-safe)
  static bool s_attr_done = false;
  if (!s_attr_done) {
    (void)hipFuncSetAttribute(reinterpret_cast<const void*>(fused_step),
                              hipFuncAttributeMaxDynamicSharedMemorySize, FUS_LDS);
    s_attr_done = true;
  }

  int* flag = (int*)(ws + OFF_FLAG);
  float* hstate = (float*)(ws + OFF_HST);
  unsigned short* rep  = (unsigned short*)(ws + OFF_REP);
  unsigned short* hid  = (unsigned short*)(ws + OFF_HID);
  unsigned short* WihF = (unsigned short*)(ws + OFF_WIHF);
  unsigned short* WhhF = (unsigned short*)(ws + OFF_WHHF);
  unsigned short* WihB = (unsigned short*)(ws + OFF_WIHB);
  unsigned short* WhhB = (unsigned short*)(ws + OFF_WHHB);
  unsigned short* bihF = (unsigned short*)(ws + OFF_BIHF);
  unsigned short* bhhF = (unsigned short*)(ws + OFF_BHHF);
  unsigned short* bihB = (unsigned short*)(ws + OFF_BIHB);
  unsigned short* bhhB = (unsigned short*)(ws + OFF_BHHB);
  unsigned short* W1C  = (unsigned short*)(ws + OFF_W1);
  unsigned short* b1C  = (unsigned short*)(ws + OFF_B1);
  unsigned short* W2C  = (unsigned short*)(ws + OFF_W2);
  unsigned short* b2C  = (unsigned short*)(ws + OFF_B2);
  unsigned short* embC = (unsigned short*)(ws + OFF_EMB);

  detect<<<1, 256, 0, stream>>>((const unsigned int*)d_in[4], flag);
  Ptrs ps;
  ps.p[0] = d_in[3];  ps.p[1] = d_in[4];  ps.p[2] = d_in[7];  ps.p[3] = d_in[8];
  ps.p[4] = d_in[5];  ps.p[5] = d_in[6];  ps.p[6] = d_in[9];  ps.p[7] = d_in[10];
  ps.p[8] = d_in[11]; ps.p[9] = d_in[12]; ps.p[10] = d_in[13]; ps.p[11] = d_in[14];
  cvt_seg<<<dim3(64, 12), 256, 0, stream>>>(ps, ws, flag);
  cvt_emb<<<2048, 256, 0, stream>>>(d_in[2], embC, flag);

  zerok<<<128, 256, 0, stream>>>((uint4*)hstate, 32768);

  // Tc: ping-pong fp32 gi needs OFF_GI + 4*Tc*786432 bytes
  int Tc = 4;
  const int cands[4] = {32, 16, 8, 4};
  for (int i = 0; i < 4; ++i) {
    if (OFF_GI + 4ull * (size_t)cands[i] * 786432ull <= ws_size) { Tc = cands[i]; break; }
  }
  float* gi0 = (float*)(ws + OFF_GI);
  float* gi1 = gi0 + 2ull * (size_t)Tc * 196608ull;

  // prologue: chunk 0 into gi0
  gi_gemm<<<dim3(6, Tc * 2, 2), 512, 0, stream>>>(seqs, lens, embC, WihF, WihB,
      gi0, gi0 + (size_t)Tc * 196608ull, 0, 512 - Tc);

  const int NC = 512 / Tc;
  for (int c = 0; c < NC; ++c) {
    float* rd = (c & 1) ? gi1 : gi0;
    float* wr = (c & 1) ? gi0 : gi1;
    const int t0f = c * Tc;
    const int t0b = 512 - (c + 1) * Tc;
    const int t0fg = (c + 1) * Tc;
    const int t0bg = 512 - (c + 2) * Tc;
    fused_step<<<128 + 24 * Tc, 256, FUS_LDS, stream>>>(
        seqs, lens, embC, WihF, WihB, WhhF, WhhB,
        bihF, bhhF, bihB, bhhB, rd, wr, hstate, rep,
        t0f, t0b, t0fg, t0bg, Tc, (c + 1 < NC) ? 1 : 0);
  }
  head1<<<dim3(16, 2), 256, 0, stream>>>(rep, W1C, b1C, hid);
  head2<<<256, 64, 0, stream>>>(hid, W2C, b2C, d_out, flag);
}

// Round 11
// 1061.022 us; speedup vs baseline: 2.5800x; 1.0439x over previous
//
#include <hip/hip_runtime.h>
#include <hip/hip_bf16.h>
#include <stdint.h>

// ---------------------------------------------------------------------------
// EncoderRNN: embedding-gather + bidirectional GRU (T=512,B=256,H=E=256) +
// tanh FC (512->512) + softmax FC (512->10).
//
// R15: R14's int8 Whh failed absmax (4.4e-3 > 2.8e-3; h-quant noise is
// irreducible within i8/fp8) -> revert to R13's bf16 numerics (passed,
// 1107us). New single variable: R13's 64KB STATIC LDS let a gemm block
// co-reside on every rec CU (2 blocks/CU at 160KB), stealing the per-SIMD
// matrix pipe from rec's serial chain (step 1.78 -> 2.1us, dispatch 57 ->
// 68us). Fix: 96KB DYNAMIC LDS -> 1 block/CU. Rec blocks (blockIdx 0..127,
// dispatched first) own their CUs; gemm cycles on the other 128 CUs
// (~25-40us, hidden under rec's ~57us). All else byte-identical to R13.
// ---------------------------------------------------------------------------

using short8  = __attribute__((ext_vector_type(8))) short;
using float4v = __attribute__((ext_vector_type(4))) float;

// ws layout (bytes)
constexpr size_t OFF_FLAG = 0;
constexpr size_t OFF_HST  = 64;                      // fp32 [2][256][256]
constexpr size_t OFF_REP  = OFF_HST  + 524288;       // bf16 [256][512]
constexpr size_t OFF_HID  = OFF_REP  + 262144;       // bf16 [256][512]
constexpr size_t OFF_WIHF = OFF_HID  + 262144;       // bf16 [768][256]
constexpr size_t OFF_WHHF = OFF_WIHF + 393216;
constexpr size_t OFF_WIHB = OFF_WHHF + 393216;
constexpr size_t OFF_WHHB = OFF_WIHB + 393216;
constexpr size_t OFF_BIHF = OFF_WHHB + 393216;       // bf16 [768]
constexpr size_t OFF_BHHF = OFF_BIHF + 1536;
constexpr size_t OFF_BIHB = OFF_BHHF + 1536;
constexpr size_t OFF_BHHB = OFF_BIHB + 1536;
constexpr size_t OFF_W1   = OFF_BHHB + 1536;         // bf16 [512][512]
constexpr size_t OFF_B1   = OFF_W1   + 524288;       // bf16 [512]
constexpr size_t OFF_W2   = OFF_B1   + 1024;         // bf16 [10][512]
constexpr size_t OFF_B2   = OFF_W2   + 10240;        // bf16 [10]
constexpr size_t OFF_EMB  = OFF_B2   + 64;           // bf16 [50000][256]
constexpr size_t OFF_GI   = OFF_EMB  + 25600000;     // fp32 gi ping-pong

// rec gi LDS: 4 rows x 3088B per buffer, 4 buffers (3-ahead pipeline)
constexpr int GI_ROWB = 3088;                        // 772 dw (2-way banks)
constexpr int GI_BUF4 = 4 * GI_ROWB;                 // 12352
// rec arena needs 16384 + 4*GI_BUF4 = 65792; gemm lA needs 64K.
// Allocate 96KB so only ONE block fits per CU (160KB pool): rec CUs are
// exclusive -- no gemm co-resident stealing the matrix pipe.
constexpr int FUS_LDS = 98304;

__device__ inline float asf(unsigned int u) {
  union { unsigned int i; float f; } v; v.i = u; return v.f;
}
__device__ inline float bf2f(unsigned short u) {
  return asf(((unsigned int)u) << 16);
}
__device__ inline unsigned short f2bf(float f) {
  union { float f; unsigned int i; } v; v.f = f;
  unsigned int i = v.i;
  return (unsigned short)((i + 0x7FFFu + ((i >> 16) & 1u)) >> 16);  // RNE
}
__device__ inline float fast_sigmoid(float x) {
  float e = __builtin_amdgcn_exp2f(-1.442695040888963f * x);
  return __builtin_amdgcn_rcpf(1.0f + e);
}
__device__ inline float fast_tanh(float x) {
  float e = __builtin_amdgcn_exp2f(2.885390081777927f * x);
  return 1.0f - 2.0f * __builtin_amdgcn_rcpf(e + 1.0f);
}

// MFMA with acc pinned to arch VGPRs; B operand VGPR- or AGPR-resident.
__device__ __forceinline__ void mfma_vv(float4v& acc, short8 a, short8 b) {
  asm("v_mfma_f32_16x16x32_bf16 %0, %1, %2, %0" : "+v"(acc) : "v"(a), "v"(b));
}
__device__ __forceinline__ void mfma_va(float4v& acc, short8 a, short8 b) {
  asm("v_mfma_f32_16x16x32_bf16 %0, %1, %2, %0" : "+v"(acc) : "v"(a), "a"(b));
}
#define PIN_AGPR(x) asm("" : "+a"(x))

// async global->LDS DMA, 16B per lane, LDS dest = uniform base + lane*16
__device__ __forceinline__ void async_copy16(char* lds, const char* g) {
  __builtin_amdgcn_global_load_lds(
      (const __attribute__((address_space(1))) unsigned int*)g,
      (__attribute__((address_space(3))) unsigned int*)lds, 16, 0, 0);
}

// ---------------------------------------------------------------------------
__global__ void detect(const unsigned int* __restrict__ w, int* __restrict__ flag) {
  __shared__ int bad;
  if (threadIdx.x == 0) bad = 0;
  __syncthreads();
  int local = 0;
  for (int i = threadIdx.x; i < 4096; i += 256) {
    const unsigned int x = w[i];
    if (((x >> 7) & 0xFFu) > 0x7Bu) local = 1;
  }
  if (local) atomicOr(&bad, 1);
  __syncthreads();
  if (threadIdx.x == 0) flag[0] = bad ? 1 : 0;
}

struct Ptrs { const void* p[12]; };

__global__ __launch_bounds__(256) void cvt_seg(Ptrs ps, char* __restrict__ wsb,
                                               const int* __restrict__ flag) {
  const int cnt[12] = {196608, 196608, 196608, 196608, 768, 768, 768, 768,
                       262144, 512, 5120, 10};
  const int off[12] = {(int)OFF_WIHF, (int)OFF_WHHF, (int)OFF_WIHB, (int)OFF_WHHB,
                       (int)OFF_BIHF, (int)OFF_BHHF, (int)OFF_BIHB, (int)OFF_BHHB,
                       (int)OFF_W1,   (int)OFF_B1,   (int)OFF_W2,   (int)OFF_B2};
  const int seg = blockIdx.y;
  const int n = cnt[seg];
  unsigned short* dst = (unsigned short*)(wsb + off[seg]);
  const int stride = gridDim.x * blockDim.x;
  int i = blockIdx.x * blockDim.x + threadIdx.x;
  if (flag[0]) {
    const float* s = (const float*)ps.p[seg];
    for (; i < n; i += stride) dst[i] = f2bf(s[i]);
  } else {
    const unsigned short* s = (const unsigned short*)ps.p[seg];
    for (; i < n; i += stride) dst[i] = s[i];
  }
}

__global__ __launch_bounds__(256) void cvt_emb(const void* __restrict__ src,
                                               unsigned short* __restrict__ dst,
                                               const int* __restrict__ flag) {
  const int n = 12800000;
  const int stride = gridDim.x * blockDim.x;
  int i = blockIdx.x * blockDim.x + threadIdx.x;
  if (flag[0]) {
    const float* s = (const float*)src;
    for (; i < n; i += stride) dst[i] = f2bf(s[i]);
  } else {
    const unsigned short* s = (const unsigned short*)src;
    for (; i < n; i += stride) dst[i] = s[i];
  }
}

// ---------------------------------------------------------------------------
__global__ void zerok(uint4* __restrict__ p, int n4) {
  int i = blockIdx.x * blockDim.x + threadIdx.x;
  if (i < n4) { uint4 z; z.x = z.y = z.z = z.w = 0u; p[i] = z; }
}

// ---------------------------------------------------------------------------
// standalone gi GEMM (prologue, chunk 0). fp32 out via nt stores.
// grid = (6, Tc*2, 2), block = 512.
__global__ __launch_bounds__(512, 4) void gi_gemm(
    const int* __restrict__ seqs, const int* __restrict__ lens,
    const unsigned short* __restrict__ emb,
    const unsigned short* __restrict__ WihF, const unsigned short* __restrict__ WihB,
    float* __restrict__ giF, float* __restrict__ giB,
    int t0f, int t0b)
{
  const int dir = blockIdx.z;
  const int nblk = blockIdx.x;
  const int tl = blockIdx.y >> 1;
  const int bh = blockIdx.y & 1;
  const int t = (dir ? t0b : t0f) + tl;

  int lo = 0, hi = 256;
  while (lo < hi) { int mid = (lo + hi) >> 1; if (lens[mid] > t) lo = mid + 1; else hi = mid; }
  const int n1 = lo;
  lo = 0; hi = 256;
  const int thr2 = 512 - t;
  while (lo < hi) { int mid = (lo + hi) >> 1; if (lens[mid] >= thr2) lo = mid + 1; else hi = mid; }
  const int n2 = lo;
  const int nneed = n1 < n2 ? n1 : n2;
  if (nneed <= bh * 128) return;

  const unsigned short* Wih = dir ? WihB : WihF;
  float* gi = dir ? giB : giF;

  __shared__ __attribute__((aligned(16))) short lA[128 * 256];

  const int tid = threadIdx.x;
  {
    const int kb = tid & 31;
    const int m0 = tid >> 5;
#pragma unroll
    for (int it = 0; it < 8; ++it) {
      const int m = it * 16 + m0;
      const int b = bh * 128 + m;
      const int tok = seqs[b * 512 + t];
      const uint4 v = *(const uint4*)(const void*)(emb + (size_t)tok * 256 + kb * 8);
      *(uint4*)(void*)(&lA[m * 256 + ((kb ^ (m & 7)) << 3)]) = v;
    }
  }
  __syncthreads();

  const int w = tid >> 6, lane = tid & 63, q = lane >> 4, n16 = lane & 15;
  const int mrow0 = (w & 3) * 32;
  const int ncol0 = (w >> 2) * 64;

  float4v acc[2][4];
#pragma unroll
  for (int mt = 0; mt < 2; ++mt)
#pragma unroll
    for (int nt = 0; nt < 4; ++nt) { float4v z = {0.f, 0.f, 0.f, 0.f}; acc[mt][nt] = z; }

#pragma unroll
  for (int ks = 0; ks < 8; ++ks) {
    short8 a[2];
#pragma unroll
    for (int mt = 0; mt < 2; ++mt) {
      const int m = mrow0 + mt * 16 + n16;
      const int kb = (ks * 4 + q) ^ (m & 7);
      a[mt] = *(const short8*)(const void*)(&lA[m * 256 + kb * 8]);
    }
#pragma unroll
    for (int nt = 0; nt < 4; ++nt) {
      const int j = nblk * 128 + ncol0 + nt * 16 + n16;
      const short8 bfr = *(const short8*)(const void*)(Wih + (size_t)j * 256 + ks * 32 + q * 8);
#pragma unroll
      for (int mt = 0; mt < 2; ++mt)
        acc[mt][nt] = __builtin_amdgcn_mfma_f32_16x16x32_bf16(a[mt], bfr, acc[mt][nt], 0, 0, 0);
    }
  }

#pragma unroll
  for (int mt = 0; mt < 2; ++mt)
#pragma unroll
    for (int nt = 0; nt < 4; ++nt)
#pragma unroll
      for (int r = 0; r < 4; ++r) {
        const int row = mrow0 + mt * 16 + q * 4 + r;
        const int b = bh * 128 + row;
        const int j = nblk * 128 + ncol0 + nt * 16 + n16;
        __builtin_nontemporal_store(acc[mt][nt][r],
            &gi[((size_t)tl * 256 + b) * 768 + j]);
      }
}

// ---------------------------------------------------------------------------
// Fused: blocks 0..127 = GRU recurrence chunk c (R12 rec code);
//        blocks 128..128+24*Tc-1 = gi GEMM chunk c+1 (M=128 x N=128 tiles).
// block = 256, dynamic LDS = FUS_LDS (96KB -> 1 block/CU, rec CUs exclusive),
// launch_bounds(256,1) -> 512-reg budget.
__global__ __launch_bounds__(256, 1) void fused_step(
    const int* __restrict__ seqs, const int* __restrict__ lens,
    const unsigned short* __restrict__ emb,
    const unsigned short* __restrict__ WihF, const unsigned short* __restrict__ WihB,
    const unsigned short* __restrict__ WhhF, const unsigned short* __restrict__ WhhB,
    const unsigned short* __restrict__ bihF, const unsigned short* __restrict__ bhhF,
    const unsigned short* __restrict__ bihB, const unsigned short* __restrict__ bhhB,
    const float* __restrict__ gi_rd, float* __restrict__ gi_wr,
    float* __restrict__ hstate, unsigned short* __restrict__ rep,
    int t0f, int t0b, int t0f_g, int t0b_g, int Tc, int do_gemm)
{
  extern __shared__ char smem[];
  const int bid = blockIdx.x;
  const int tid = threadIdx.x, w = tid >> 6, lane = tid & 63, q = lane >> 4, n16 = lane & 15;

  if (bid < 128) {
    // ------------------------- recurrence (chunk c) -------------------------
    const int d = bid >> 6;
    const int g4 = bid & 63;

    const unsigned short* Whh = d ? WhhB : WhhF;
    const unsigned short* bih = d ? bihB : bihF;
    const unsigned short* bhh = d ? bhhB : bhhF;
    const float* gi = gi_rd + (size_t)d * (size_t)Tc * 196608;
    const int t0 = d ? t0b : t0f;

    short* hB0 = (short*)smem;            // 8KB [16][256] swizzled
    short* hB1 = (short*)(smem + 8192);   // 8KB
    char*  giL = smem + 16384;            // 4 x GI_BUF4

    // zero hB0+hB1 (rows != 4q feed the MFMA A-tile and must stay zero)
    {
      uint4 z; z.x = z.y = z.z = z.w = 0u;
      uint4* p = (uint4*)(void*)smem;
      for (int i = tid; i < 1024; i += 256) p[i] = z;   // 16KB
    }

    // async prefetch of one gi tile (4 rows x 3072B); wave w loads row w.
    auto prefetch_gi = [&](int buf, int tl) {
      const char* srcB = (const char*)(gi + ((size_t)tl * 256 + g4 * 4) * 768);
      char* dstB = giL + buf * GI_BUF4;
#pragma unroll
      for (int i = 0; i < 3; ++i)
        async_copy16(dstB + w * GI_ROWB + i * 1024,
                     srcB + w * 3072 + i * 1024 + lane * 16);
    };

    // --- weight fragments: pair p = ct4*3+gate, wave w owns h-cols [4w..4w+4)*16
    const unsigned short* wbase = Whh + (size_t)q * 8;  // + j*256 + ks*32
    // pairs 0..3 -> VGPR file
    short8 wV[4][8];
#pragma unroll
    for (int p = 0; p < 4; ++p) {
      const int ct4 = p / 3, gate = p % 3;
      const int j = gate * 256 + (w * 4 + ct4) * 16 + n16;
#pragma unroll
      for (int ks = 0; ks < 8; ++ks)
        wV[p][ks] = *(const short8*)(const void*)(wbase + (size_t)j * 256 + ks * 32);
    }
    // pairs 4..11 -> AGPR file (pinned at init; only "a" uses below)
    short8 wA[8][8];
#pragma unroll
    for (int p8 = 0; p8 < 8; ++p8) {
      const int p = p8 + 4;
      const int ct4 = p / 3, gate = p % 3;
      const int j = gate * 256 + (w * 4 + ct4) * 16 + n16;
#pragma unroll
      for (int ks = 0; ks < 8; ++ks) {
        wA[p8][ks] = *(const short8*)(const void*)(wbase + (size_t)j * 256 + ks * 32);
        PIN_AGPR(wA[p8][ks]);
      }
    }

    float cr[4], cz[4], bin_[4], bhn_[4];
#pragma unroll
    for (int ct4 = 0; ct4 < 4; ++ct4) {
      const int j16 = (w * 4 + ct4) * 16 + n16;
      cr[ct4]   = bf2f(bih[j16])       + bf2f(bhh[j16]);
      cz[ct4]   = bf2f(bih[256 + j16]) + bf2f(bhh[256 + j16]);
      bin_[ct4] = bf2f(bih[512 + j16]);
      bhn_[ct4] = bf2f(bhh[512 + j16]);
    }

    const int mylen = lens[g4 * 4 + q];   // this lane's batch row = q
    const int row4 = 4 * q;               // hB row for this lane's batch row

    float h[4];
#pragma unroll
    for (int ct4 = 0; ct4 < 4; ++ct4) {
      const int col = (w * 4 + ct4) * 16 + n16;
      h[ct4] = hstate[d * 65536 + (g4 * 4 + q) * 256 + col];
    }

    __syncthreads();  // hB zero-init visible before data-row writes

#pragma unroll
    for (int ct4 = 0; ct4 < 4; ++ct4) {
      const int col = (w * 4 + ct4) * 16 + n16;
      const int kb = col >> 3;
      hB0[row4 * 256 + ((kb ^ (row4 & 7)) << 3) + (col & 7)] = (short)f2bf(h[ct4]);
    }
    // fill pipeline: tiles for steps 0,1,2
    for (int a = 0; a < 3; ++a) {
      const int tl = (a < Tc) ? (d ? (Tc - 1 - a) : a) : 0;
      prefetch_gi(a, tl);
    }
    __syncthreads();  // full drain once (prologue only); hB0 visible

    for (int s = 0; s < Tc; ++s) {
      const int t = t0 + (d ? (Tc - 1 - s) : s);

      // issue prefetch 3 steps ahead (clamped dummy at tail)
      {
        const int sa = s + 3;
        const int tla = (sa < Tc) ? (d ? (Tc - 1 - sa) : sa) : 0;
        prefetch_gi(sa & 3, tla);
      }

      // this step's gi tile -> registers (hidden under the MFMA block)
      const float* grow = (const float*)(void*)(giL + (s & 3) * GI_BUF4 + q * GI_ROWB);
      float gr[4], gz[4], gn[4];
#pragma unroll
      for (int ct4 = 0; ct4 < 4; ++ct4) {
        const int col = (w * 4 + ct4) * 16 + n16;
        gr[ct4] = grow[col];
        gz[ct4] = grow[256 + col];
        gn[ct4] = grow[512 + col];
      }

      const short* hRd = (s & 1) ? hB1 : hB0;
      short* hWr = (s & 1) ? hB0 : hB1;

      float4v acc[12];
#pragma unroll
      for (int p = 0; p < 12; ++p) { float4v z = {0.f, 0.f, 0.f, 0.f}; acc[p] = z; }

#pragma unroll
      for (int ks = 0; ks < 8; ++ks) {
        const int kb = (ks * 4 + q) ^ (n16 & 7);
        const short8 a = *(const short8*)(const void*)(&hRd[n16 * 256 + kb * 8]);
#pragma unroll
        for (int p = 0; p < 4; ++p) mfma_vv(acc[p], a, wV[p][ks]);
#pragma unroll
        for (int p8 = 0; p8 < 8; ++p8) mfma_va(acc[p8 + 4], a, wA[p8][ks]);
      }

      // all-lane epilogue: lane owns (batch row q, col n16); C row 4q -> reg 0
      const bool act = (t < mylen);
      const bool ug  = (t >= 512 - mylen);
#pragma unroll
      for (int ct4 = 0; ct4 < 4; ++ct4) {
        const int col = (w * 4 + ct4) * 16 + n16;
        const int kb = col >> 3;
        const float grv = ug ? gr[ct4] : 0.f;
        const float gzv = ug ? gz[ct4] : 0.f;
        const float gnv = ug ? gn[ct4] : 0.f;
        const float rr = fast_sigmoid(grv + cr[ct4] + acc[ct4 * 3 + 0][0]);
        const float zz = fast_sigmoid(gzv + cz[ct4] + acc[ct4 * 3 + 1][0]);
        const float nn = fast_tanh(gnv + bin_[ct4] + rr * (acc[ct4 * 3 + 2][0] + bhn_[ct4]));
        const float hnew = zz * (h[ct4] - nn) + nn;
        h[ct4] = act ? hnew : h[ct4];
        hWr[row4 * 256 + ((kb ^ (row4 & 7)) << 3) + (col & 7)] = (short)f2bf(h[ct4]);
      }

      // ONE barrier/step: drains hWr (lgkm) + gi tile for s+1 (vmcnt(6) keeps
      // only the 6 loads from steps s-1,s in flight).
      asm volatile("s_waitcnt vmcnt(6) lgkmcnt(0)" ::: "memory");
      __builtin_amdgcn_s_barrier();
    }

#pragma unroll
    for (int ct4 = 0; ct4 < 4; ++ct4) {
      const int col = (w * 4 + ct4) * 16 + n16;
      const int b = g4 * 4 + q;
      hstate[d * 65536 + b * 256 + col] = h[ct4];
      rep[b * 512 + d * 256 + col] = f2bf(h[ct4]);
    }
    return;
  }

  // ------------------------- gi GEMM (chunk c+1) -------------------------
  if (!do_gemm) return;
  const int g2 = bid - 128;
  const int nblk = g2 % 6;              // N-block of 128 gate-cols
  const int rest = g2 / 6;
  const int yy = rest % (2 * Tc);
  const int dirg = rest / (2 * Tc);
  const int tl = yy >> 1;
  const int bh = yy & 1;
  const int t = (dirg ? t0b_g : t0f_g) + tl;

  int lo = 0, hi = 256;
  while (lo < hi) { int mid = (lo + hi) >> 1; if (lens[mid] > t) lo = mid + 1; else hi = mid; }
  const int n1 = lo;
  lo = 0; hi = 256;
  const int thr2 = 512 - t;
  while (lo < hi) { int mid = (lo + hi) >> 1; if (lens[mid] >= thr2) lo = mid + 1; else hi = mid; }
  const int n2 = lo;
  const int nneed = n1 < n2 ? n1 : n2;
  if (nneed <= bh * 128) return;

  const unsigned short* Wih = dirg ? WihB : WihF;
  float* gi = gi_wr + (size_t)dirg * (size_t)Tc * 196608;

  short* lA = (short*)(void*)smem;  // 64KB [128][256] swizzled

  {
    const int kb = tid & 31;
    const int m0 = tid >> 5;  // 0..7
#pragma unroll
    for (int it = 0; it < 16; ++it) {
      const int m = it * 8 + m0;
      const int b = bh * 128 + m;
      const int tok = seqs[b * 512 + t];
      const uint4 v = *(const uint4*)(const void*)(emb + (size_t)tok * 256 + kb * 8);
      *(uint4*)(void*)(&lA[m * 256 + ((kb ^ (m & 7)) << 3)]) = v;
    }
  }
  __syncthreads();

  const int mrow0 = w * 32;

  float4v acc[2][8];
#pragma unroll
  for (int mt = 0; mt < 2; ++mt)
#pragma unroll
    for (int nt = 0; nt < 8; ++nt) { float4v z = {0.f, 0.f, 0.f, 0.f}; acc[mt][nt] = z; }

#pragma unroll
  for (int ks = 0; ks < 8; ++ks) {
    short8 a[2];
#pragma unroll
    for (int mt = 0; mt < 2; ++mt) {
      const int m = mrow0 + mt * 16 + n16;
      const int kb = (ks * 4 + q) ^ (m & 7);
      a[mt] = *(const short8*)(const void*)(&lA[m * 256 + kb * 8]);
    }
#pragma unroll
    for (int nt = 0; nt < 8; ++nt) {
      const int j = nblk * 128 + nt * 16 + n16;
      const short8 bfr = *(const short8*)(const void*)(Wih + (size_t)j * 256 + ks * 32 + q * 8);
#pragma unroll
      for (int mt = 0; mt < 2; ++mt)
        mfma_vv(acc[mt][nt], a[mt], bfr);
    }
  }

#pragma unroll
  for (int mt = 0; mt < 2; ++mt)
#pragma unroll
    for (int nt = 0; nt < 8; ++nt)
#pragma unroll
      for (int r = 0; r < 4; ++r) {
        const int row = mrow0 + mt * 16 + q * 4 + r;
        const int b = bh * 128 + row;
        const int j = nblk * 128 + nt * 16 + n16;
        __builtin_nontemporal_store(acc[mt][nt][r],
            &gi[((size_t)tl * 256 + b) * 768 + j]);
      }
}

// ---------------------------------------------------------------------------
__global__ __launch_bounds__(256, 4) void head1(
    const unsigned short* __restrict__ rep, const unsigned short* __restrict__ W1,
    const unsigned short* __restrict__ b1, unsigned short* __restrict__ hid)
{
  const int mt = blockIdx.x;
  const int nh = blockIdx.y;
  const int tid = threadIdx.x, w = tid >> 6, lane = tid & 63, q = lane >> 4, n16 = lane & 15;

  float4v acc[4];
#pragma unroll
  for (int nt = 0; nt < 4; ++nt) { float4v z = {0.f, 0.f, 0.f, 0.f}; acc[nt] = z; }

#pragma unroll
  for (int ks = 0; ks < 16; ++ks) {
    const short8 a = *(const short8*)(const void*)(rep + (size_t)(mt * 16 + n16) * 512 + ks * 32 + q * 8);
#pragma unroll
    for (int nt = 0; nt < 4; ++nt) {
      const int n = nh * 256 + w * 64 + nt * 16 + n16;
      const short8 bfr = *(const short8*)(const void*)(W1 + (size_t)n * 512 + ks * 32 + q * 8);
      acc[nt] = __builtin_amdgcn_mfma_f32_16x16x32_bf16(a, bfr, acc[nt], 0, 0, 0);
    }
  }
#pragma unroll
  for (int nt = 0; nt < 4; ++nt)
#pragma unroll
    for (int r = 0; r < 4; ++r) {
      const int row = mt * 16 + q * 4 + r;
      const int col = nh * 256 + w * 64 + nt * 16 + n16;
      hid[row * 512 + col] = f2bf(fast_tanh(acc[nt][r] + bf2f(b1[col])));
    }
}

// ---------------------------------------------------------------------------
__global__ __launch_bounds__(64, 4) void head2(
    const unsigned short* __restrict__ hid, const unsigned short* __restrict__ W2,
    const unsigned short* __restrict__ b2, void* __restrict__ out,
    const int* __restrict__ flag)
{
  const int row = blockIdx.x;
  const int lane = threadIdx.x;
  const uint4 hv = *(const uint4*)(const void*)(hid + (size_t)row * 512 + lane * 8);
  const unsigned int hu[4] = {hv.x, hv.y, hv.z, hv.w};

  float logit[10];
#pragma unroll
  for (int j = 0; j < 10; ++j) {
    const uint4 wv = *(const uint4*)(const void*)(W2 + (size_t)j * 512 + lane * 8);
    const unsigned int wu[4] = {wv.x, wv.y, wv.z, wv.w};
    float s = 0.f;
#pragma unroll
    for (int i = 0; i < 4; ++i) {
      s = fmaf(asf(hu[i] << 16), asf(wu[i] << 16), s);
      s = fmaf(asf(hu[i] & 0xffff0000u), asf(wu[i] & 0xffff0000u), s);
    }
#pragma unroll
    for (int off = 32; off > 0; off >>= 1) s += __shfl_xor(s, off);
    logit[j] = s + bf2f(b2[j]);
  }
  float mx = logit[0];
#pragma unroll
  for (int j = 1; j < 10; ++j) mx = fmaxf(mx, logit[j]);
  float e[10]; float sum = 0.f;
#pragma unroll
  for (int j = 0; j < 10; ++j) { e[j] = __builtin_amdgcn_exp2f(1.442695040888963f * (logit[j] - mx)); sum += e[j]; }
  const float rs = __builtin_amdgcn_rcpf(sum);
  if (lane < 10) {
    float p = e[0];
#pragma unroll
    for (int j = 1; j < 10; ++j) p = (lane == j) ? e[j] : p;
    if (flag[0]) ((float*)out)[row * 10 + lane] = p * rs;
    else         ((unsigned short*)out)[row * 10 + lane] = f2bf(p * rs);
  }
}

// ---------------------------------------------------------------------------
extern "C" void kernel_launch(void* const* d_in, const int* in_sizes, int n_in,
                              void* d_out, int out_size, void* d_ws, size_t ws_size,
                              hipStream_t stream)
{
  (void)in_sizes; (void)n_in; (void)out_size;
  const int* seqs = (const int*)d_in[0];
  const int* lens = (const int*)d_in[1];
  char* ws = (char*)d_ws;

  // one-time: allow >64KB dynamic LDS for fused_step (host-side, capture-safe)
  static bool s_attr_done = false;
  if (!s_attr_done) {
    (void)hipFuncSetAttribute(reinterpret_cast<const void*>(fused_step),
                              hipFuncAttributeMaxDynamicSharedMemorySize, FUS_LDS);
    s_attr_done = true;
  }

  int* flag = (int*)(ws + OFF_FLAG);
  float* hstate = (float*)(ws + OFF_HST);
  unsigned short* rep  = (unsigned short*)(ws + OFF_REP);
  unsigned short* hid  = (unsigned short*)(ws + OFF_HID);
  unsigned short* WihF = (unsigned short*)(ws + OFF_WIHF);
  unsigned short* WhhF = (unsigned short*)(ws + OFF_WHHF);
  unsigned short* WihB = (unsigned short*)(ws + OFF_WIHB);
  unsigned short* WhhB = (unsigned short*)(ws + OFF_WHHB);
  unsigned short* bihF = (unsigned short*)(ws + OFF_BIHF);
  unsigned short* bhhF = (unsigned short*)(ws + OFF_BHHF);
  unsigned short* bihB = (unsigned short*)(ws + OFF_BIHB);
  unsigned short* bhhB = (unsigned short*)(ws + OFF_BHHB);
  unsigned short* W1C  = (unsigned short*)(ws + OFF_W1);
  unsigned short* b1C  = (unsigned short*)(ws + OFF_B1);
  unsigned short* W2C  = (unsigned short*)(ws + OFF_W2);
  unsigned short* b2C  = (unsigned short*)(ws + OFF_B2);
  unsigned short* embC = (unsigned short*)(ws + OFF_EMB);

  detect<<<1, 256, 0, stream>>>((const unsigned int*)d_in[4], flag);
  Ptrs ps;
  ps.p[0] = d_in[3];  ps.p[1] = d_in[4];  ps.p[2] = d_in[7];  ps.p[3] = d_in[8];
  ps.p[4] = d_in[5];  ps.p[5] = d_in[6];  ps.p[6] = d_in[9];  ps.p[7] = d_in[10];
  ps.p[8] = d_in[11]; ps.p[9] = d_in[12]; ps.p[10] = d_in[13]; ps.p[11] = d_in[14];
  cvt_seg<<<dim3(64, 12), 256, 0, stream>>>(ps, ws, flag);
  cvt_emb<<<2048, 256, 0, stream>>>(d_in[2], embC, flag);

  zerok<<<128, 256, 0, stream>>>((uint4*)hstate, 32768);

  // Tc: ping-pong fp32 gi needs OFF_GI + 4*Tc*786432 bytes
  int Tc = 4;
  const int cands[4] = {32, 16, 8, 4};
  for (int i = 0; i < 4; ++i) {
    if (OFF_GI + 4ull * (size_t)cands[i] * 786432ull <= ws_size) { Tc = cands[i]; break; }
  }
  float* gi0 = (float*)(ws + OFF_GI);
  float* gi1 = gi0 + 2ull * (size_t)Tc * 196608ull;

  // prologue: chunk 0 into gi0
  gi_gemm<<<dim3(6, Tc * 2, 2), 512, 0, stream>>>(seqs, lens, embC, WihF, WihB,
      gi0, gi0 + (size_t)Tc * 196608ull, 0, 512 - Tc);

  const int NC = 512 / Tc;
  for (int c = 0; c < NC; ++c) {
    float* rd = (c & 1) ? gi1 : gi0;
    float* wr = (c & 1) ? gi0 : gi1;
    const int t0f = c * Tc;
    const int t0b = 512 - (c + 1) * Tc;
    const int t0fg = (c + 1) * Tc;
    const int t0bg = 512 - (c + 2) * Tc;
    fused_step<<<128 + 24 * Tc, 256, FUS_LDS, stream>>>(
        seqs, lens, embC, WihF, WihB, WhhF, WhhB,
        bihF, bhhF, bihB, bhhB, rd, wr, hstate, rep,
        t0f, t0b, t0fg, t0bg, Tc, (c + 1 < NC) ? 1 : 0);
  }
  head1<<<dim3(16, 2), 256, 0, stream>>>(rep, W1C, b1C, hid);
  head2<<<256, 64, 0, stream>>>(hid, W2C, b2C, d_out, flag);
}